// Round 10
// baseline (29466.644 us; speedup 1.0000x reference)
//
#include <hip/hip_runtime.h>
#include <math.h>

#define Tn 256
#define Bn 64
#define Hn 512
#define CHUNK 64
#define EPSF 1e-15f
#define LOG2E 1.4426950408889634f

typedef float f32x2 __attribute__((ext_vector_type(2)));

// ---- hardware transcendentals with series guards ----
__device__ __forceinline__ float exp2_hw(float x){ float r; asm("v_exp_f32 %0, %1" : "=v"(r) : "v"(x)); return r; }
__device__ __forceinline__ float log2_hw(float x){ float r; asm("v_log_f32 %0, %1" : "=v"(r) : "v"(x)); return r; }
__device__ __forceinline__ float rcp_hw (float x){ float r; asm("v_rcp_f32 %0, %1" : "=v"(r) : "v"(x)); return r; }

__device__ __forceinline__ float artanh_fast(float x){   // x >= 0
  const float xc = fminf(x, 1.0f - 1e-7f);
  const float big = 0.34657359028f * (log2_hw(1.f + xc) - log2_hw(1.f - xc));
  const float x2 = x*x;
  const float small = x*(1.f + x2*(0.33333333f + x2*0.2f));
  return (x < 0.01f) ? small : big;
}
__device__ __forceinline__ float tanh_fast(float y){     // y >= 0
  const float t = exp2_hw(-2.f*LOG2E*y);
  const float big = (1.f - t) / (1.f + t);
  const float small = y*(1.f - 0.33333333f*y*y);
  return (y < 0.01f) ? small : big;
}
__device__ __forceinline__ float sigmoid_fast(float x){
  return rcp_hw(1.f + exp2_hw(-LOG2E*x));
}

// full-wave butterfly reduce of N values.
template<int N>
__device__ __forceinline__ void red64N(float* v){
  #pragma unroll
  for (int off = 1; off < 64; off <<= 1){
    #pragma unroll
    for (int n = 0; n < N; ++n) v[n] += __shfl_xor(v[n], off);
  }
}

template<int N>
__device__ __forceinline__ void block_reduceN(float* v, float* red){
  #pragma unroll
  for (int off = 32; off > 0; off >>= 1){
    #pragma unroll
    for (int n = 0; n < N; ++n) v[n] += __shfl_xor(v[n], off);
  }
  const int tid = threadIdx.x;
  const int w = tid >> 6;
  __syncthreads();
  if ((tid & 63) == 0){
    #pragma unroll
    for (int n = 0; n < N; ++n) red[n*4 + w] = v[n];
  }
  __syncthreads();
  #pragma unroll
  for (int n = 0; n < N; ++n)
    v[n] = red[n*4+0] + red[n*4+1] + red[n*4+2] + red[n*4+3];
}

// ---------------- precompute GEMM ------------------------------------------
#define GBM 64
#define GBN 64
#define GBK 16

__global__ __launch_bounds__(256) void gemm_tn(
    const float* __restrict__ A, const float* __restrict__ Bm,
    float* __restrict__ Cm)
{
  __shared__ __align__(16) float As[GBK][GBM];
  __shared__ __align__(16) float Bs[GBK][GBN];
  const int tid = threadIdx.x;
  const int rm0 = blockIdx.x * GBM;
  const int cn0 = blockIdx.y * GBN;
  const int lr = tid >> 2;
  const int lk = (tid & 3) * 4;
  const int tx = tid & 15;
  const int ty = tid >> 4;
  float acc[4][4] = {};
  const float* Arow = A  + (size_t)(rm0 + lr) * 512 + lk;
  const float* Brow = Bm + (size_t)(cn0 + lr) * 512 + lk;
  for (int k0 = 0; k0 < 512; k0 += GBK){
    const float4 av = *reinterpret_cast<const float4*>(Arow + k0);
    const float4 bv = *reinterpret_cast<const float4*>(Brow + k0);
    __syncthreads();
    As[lk+0][lr]=av.x; As[lk+1][lr]=av.y; As[lk+2][lr]=av.z; As[lk+3][lr]=av.w;
    Bs[lk+0][lr]=bv.x; Bs[lk+1][lr]=bv.y; Bs[lk+2][lr]=bv.z; Bs[lk+3][lr]=bv.w;
    __syncthreads();
    #pragma unroll
    for (int kk = 0; kk < GBK; ++kk){
      const float4 a4 = *reinterpret_cast<const float4*>(&As[kk][tx*4]);
      const float4 b4 = *reinterpret_cast<const float4*>(&Bs[kk][ty*4]);
      const float ar[4] = {a4.x, a4.y, a4.z, a4.w};
      const float br[4] = {b4.x, b4.y, b4.z, b4.w};
      #pragma unroll
      for (int i = 0; i < 4; ++i)
        #pragma unroll
        for (int j = 0; j < 4; ++j)
          acc[i][j] = fmaf(ar[i], br[j], acc[i][j]);
    }
  }
  #pragma unroll
  for (int i = 0; i < 4; ++i){
    float4 st; st.x=acc[i][0]; st.y=acc[i][1]; st.z=acc[i][2]; st.w=acc[i][3];
    *reinterpret_cast<float4*>(&Cm[(size_t)(rm0 + tx*4 + i)*1536 + cn0 + ty*4]) = st;
  }
}

// ------- mobius_matvec scaling of P rows ------------------------------------
__global__ __launch_bounds__(256) void scale_kernel(
    const float* __restrict__ src, float* __restrict__ P)
{
  __shared__ float red[24];
  const int row = blockIdx.x, tid = threadIdx.x;
  const float x0 = src[(size_t)row*512 + tid];
  const float x1 = src[(size_t)row*512 + tid + 256];
  float v[3];
  v[0] = x0*x0 + x1*x1; v[1] = 0.f; v[2] = 0.f;
  block_reduceN<3>(v, red);
  const float xn = sqrtf(v[0] + EPSF);
  const float xc = fminf(fmaxf(xn, -1.0f + 1e-7f), 1.0f - 1e-7f);
  const float artx = 0.5f * (log1pf(xc) - log1pf(-xc));
  float* Prow = P + (size_t)row*1536;
  float p[6];
  #pragma unroll
  for (int g = 0; g < 3; ++g){
    p[2*g]   = Prow[g*512 + tid];
    p[2*g+1] = Prow[g*512 + tid + 256];
  }
  float m[3];
  #pragma unroll
  for (int g = 0; g < 3; ++g) m[g] = p[2*g]*p[2*g] + p[2*g+1]*p[2*g+1];
  block_reduceN<3>(m, red);
  #pragma unroll
  for (int g = 0; g < 3; ++g){
    const float mn = sqrtf(m[g] + EPSF);
    const float s = tanhf(mn / xn * artx) / mn;
    Prow[g*512 + tid]       = s * p[2*g];
    Prow[g*512 + tid + 256] = s * p[2*g+1];
  }
}

// ---------------- persistent recurrence: 1 block = 1 batch, no grid sync -----
// 64 blocks x 512 threads (8 waves). Per step:
//   A: M_r,M_z (1024 rows, row-per-wave coalesced loads) -> LDS
//   chains: wave0 r-chain(+rh) || wave1 z-chain          -> LDS
//   C: M_h (512 rows)                                     -> LDS
//   finish: wave0 -> h_s, outseq
__global__ __launch_bounds__(512) void recur_kernel(
    const float* __restrict__ Whh,   // (1536,512): [r | hid | z]
    const float* __restrict__ bias,  // (3,512)
    const float* __restrict__ P,     // CHUNK*Bn x 1536 (scaled x-side)
    const float* __restrict__ hinit, // (B,512) previous h, or nullptr -> zeros
    float* __restrict__ outseq,      // (T,B,H)
    float* __restrict__ lastdst,     // (B,H), written at t==Tn-1
    int t0, int nsteps)
{
  __shared__ __align__(16) float h_s[Hn];
  __shared__ __align__(16) float mrz_s[1024];
  __shared__ __align__(16) float mh_s[Hn];
  __shared__ __align__(16) float rh_s[Hn];
  __shared__ __align__(16) float z_s[Hn];
  const int b   = blockIdx.x;
  const int tid = threadIdx.x;
  const int wv  = tid >> 6;     // wave 0..7
  const int l   = tid & 63;     // lane

  if (tid < Hn) h_s[tid] = hinit ? hinit[(size_t)b*Hn + tid] : 0.f;
  __syncthreads();

  // wave-0 persistent chain stats (live across phases within a step)
  float xn_rh = 0.f, artx_rh = 0.f, hn2_keep = 0.f;

  for (int tt = 0; tt < nsteps; ++tt){
    const int t = t0 + tt;
    const float* prow = P + ((size_t)tt*Bn + b)*1536;

    // ---------------- A: M_r (rows 0..511) + M_z (rows 512..1023) ----------
    {
      const float4 hA = *reinterpret_cast<const float4*>(&h_s[4*l]);
      const float4 hB = *reinterpret_cast<const float4*>(&h_s[256 + 4*l]);
      #pragma unroll 1
      for (int pass = 0; pass < 16; ++pass){
        const int rowbase = pass*64 + wv*8;
        float acc[8];
        #pragma unroll
        for (int rr = 0; rr < 8; ++rr){
          const int mrow = rowbase + rr;
          const int wrow = (mrow < 512) ? mrow : mrow + 512;
          const float4* wp = reinterpret_cast<const float4*>(Whh + (size_t)wrow*Hn);
          const float4 wa = wp[l];
          const float4 wb = wp[64 + l];
          float a = wa.x*hA.x;
          a = fmaf(wa.y, hA.y, a); a = fmaf(wa.z, hA.z, a); a = fmaf(wa.w, hA.w, a);
          a = fmaf(wb.x, hB.x, a); a = fmaf(wb.y, hB.y, a);
          a = fmaf(wb.z, hB.z, a); a = fmaf(wb.w, hB.w, a);
          acc[rr] = a;
        }
        red64N<8>(acc);
        const float out = (l==0)?acc[0]:(l==1)?acc[1]:(l==2)?acc[2]:(l==3)?acc[3]
                        :(l==4)?acc[4]:(l==5)?acc[5]:(l==6)?acc[6]:acc[7];
        if (l < 8) mrz_s[rowbase + l] = out;
      }
    }
    __syncthreads();

    // ---------------- chains: wave0 = r-chain + rh; wave1 = z-chain --------
    if (wv == 0){
      float m[8], p[8], bv[8], h[8];
      #pragma unroll
      for (int e = 0; e < 8; ++e){
        const int j = l + 64*e;
        m[e] = mrz_s[j]; p[e] = prow[j]; bv[e] = bias[j]; h[e] = h_s[j];
      }
      float v[3];
      v[0]=0.f; v[1]=0.f;
      #pragma unroll
      for (int e = 0; e < 8; ++e){ v[0]=fmaf(h[e],h[e],v[0]); v[1]=fmaf(m[e],m[e],v[1]); }
      red64N<2>(v);
      const float hn2 = v[0];
      const float xn_h = sqrtf(hn2 + EPSF);
      const float artx_h = artanh_fast(xn_h);
      const float m2 = v[1];
      const float mn = sqrtf(m2 + EPSF);
      const float s = tanh_fast(mn/xn_h*artx_h) * (1.f/mn);
      const float x2 = s*s*m2;
      v[0]=0.f; v[1]=0.f;
      #pragma unroll
      for (int e = 0; e < 8; ++e){ v[0]=fmaf(p[e],p[e],v[0]); v[1]=fmaf(s*m[e],p[e],v[1]); }
      red64N<2>(v);
      float na = 1.f + 2.f*v[1] + v[0];
      float nb = 1.f - x2;
      float rden = 1.f / fmaxf(1.f + 2.f*v[1] + x2*v[0], EPSF);
      #pragma unroll
      for (int e = 0; e < 8; ++e) p[e] = (na*s*m[e] + nb*p[e])*rden;    // q
      v[0]=0.f; v[1]=0.f; v[2]=0.f;
      #pragma unroll
      for (int e = 0; e < 8; ++e){
        v[0]=fmaf(p[e],p[e],v[0]); v[1]=fmaf(bv[e],bv[e],v[1]); v[2]=fmaf(p[e],bv[e],v[2]);
      }
      red64N<3>(v);
      na = 1.f + 2.f*v[2] + v[1];
      nb = 1.f - v[0];
      rden = 1.f / fmaxf(1.f + 2.f*v[2] + v[0]*v[1], EPSF);
      v[0] = 0.f;
      #pragma unroll
      for (int e = 0; e < 8; ++e){
        m[e] = (na*p[e] + nb*bv[e])*rden;                               // w
        v[0] = fmaf(m[e], m[e], v[0]);
      }
      red64N<1>(v);
      const float yn = sqrtf(v[0] + EPSF);
      const float sc = artanh_fast(yn) * (1.f/yn);
      v[0] = 0.f;
      #pragma unroll
      for (int e = 0; e < 8; ++e){
        const float r = sigmoid_fast(sc*m[e]);
        m[e] = r*h[e];                                                  // u
        v[0] = fmaf(m[e], m[e], v[0]);
      }
      red64N<1>(v);
      const float u2 = v[0];
      const float wn = sqrtf(u2 + EPSF);
      const float s_rh = tanh_fast(wn/xn_h*artx_h) * (1.f/wn);
      #pragma unroll
      for (int e = 0; e < 8; ++e) rh_s[l + 64*e] = s_rh*m[e];
      xn_rh = sqrtf(s_rh*s_rh*u2 + EPSF);
      artx_rh = artanh_fast(xn_rh);
      hn2_keep = hn2;
    } else if (wv == 1){
      float m[8], p[8], bv[8], h[8];
      #pragma unroll
      for (int e = 0; e < 8; ++e){
        const int j = l + 64*e;
        m[e] = mrz_s[512 + j]; p[e] = prow[1024 + j]; bv[e] = bias[1024 + j];
        h[e] = h_s[j];
      }
      float v[3];
      v[0]=0.f; v[1]=0.f;
      #pragma unroll
      for (int e = 0; e < 8; ++e){ v[0]=fmaf(h[e],h[e],v[0]); v[1]=fmaf(m[e],m[e],v[1]); }
      red64N<2>(v);
      const float hn2 = v[0];
      const float xn_h = sqrtf(hn2 + EPSF);
      const float artx_h = artanh_fast(xn_h);
      const float m2 = v[1];
      const float mn = sqrtf(m2 + EPSF);
      const float s = tanh_fast(mn/xn_h*artx_h) * (1.f/mn);
      const float x2 = s*s*m2;
      v[0]=0.f; v[1]=0.f;
      #pragma unroll
      for (int e = 0; e < 8; ++e){ v[0]=fmaf(p[e],p[e],v[0]); v[1]=fmaf(s*m[e],p[e],v[1]); }
      red64N<2>(v);
      float na = 1.f + 2.f*v[1] + v[0];
      float nb = 1.f - x2;
      float rden = 1.f / fmaxf(1.f + 2.f*v[1] + x2*v[0], EPSF);
      #pragma unroll
      for (int e = 0; e < 8; ++e) p[e] = (na*s*m[e] + nb*p[e])*rden;    // q
      v[0]=0.f; v[1]=0.f; v[2]=0.f;
      #pragma unroll
      for (int e = 0; e < 8; ++e){
        v[0]=fmaf(p[e],p[e],v[0]); v[1]=fmaf(bv[e],bv[e],v[1]); v[2]=fmaf(p[e],bv[e],v[2]);
      }
      red64N<3>(v);
      na = 1.f + 2.f*v[2] + v[1];
      nb = 1.f - v[0];
      rden = 1.f / fmaxf(1.f + 2.f*v[2] + v[0]*v[1], EPSF);
      float w2[1] = {0.f};
      #pragma unroll
      for (int e = 0; e < 8; ++e){
        m[e] = (na*p[e] + nb*bv[e])*rden;                               // w
        w2[0] = fmaf(m[e], m[e], w2[0]);
      }
      red64N<1>(w2);
      const float yn = sqrtf(w2[0] + EPSF);
      const float sc = artanh_fast(yn) * (1.f/yn);
      #pragma unroll
      for (int e = 0; e < 8; ++e) z_s[l + 64*e] = sigmoid_fast(sc*m[e]);
    }
    __syncthreads();

    // ---------------- C: M_h (W rows 512..1023, operand rh) ----------------
    {
      const float4 rA = *reinterpret_cast<const float4*>(&rh_s[4*l]);
      const float4 rB = *reinterpret_cast<const float4*>(&rh_s[256 + 4*l]);
      #pragma unroll 1
      for (int pass = 0; pass < 8; ++pass){
        const int rowbase = pass*64 + wv*8;
        float acc[8];
        #pragma unroll
        for (int rr = 0; rr < 8; ++rr){
          const float4* wp = reinterpret_cast<const float4*>(
              Whh + (size_t)(512 + rowbase + rr)*Hn);
          const float4 wa = wp[l];
          const float4 wb = wp[64 + l];
          float a = wa.x*rA.x;
          a = fmaf(wa.y, rA.y, a); a = fmaf(wa.z, rA.z, a); a = fmaf(wa.w, rA.w, a);
          a = fmaf(wb.x, rB.x, a); a = fmaf(wb.y, rB.y, a);
          a = fmaf(wb.z, rB.z, a); a = fmaf(wb.w, rB.w, a);
          acc[rr] = a;
        }
        red64N<8>(acc);
        const float out = (l==0)?acc[0]:(l==1)?acc[1]:(l==2)?acc[2]:(l==3)?acc[3]
                        :(l==4)?acc[4]:(l==5)?acc[5]:(l==6)?acc[6]:acc[7];
        if (l < 8) mh_s[rowbase + l] = out;
      }
    }
    __syncthreads();

    // ---------------- finish (wave 0) --------------------------------------
    if (wv == 0){
      float m[8], p[8], bv[8], h[8], z[8];
      #pragma unroll
      for (int e = 0; e < 8; ++e){
        const int j = l + 64*e;
        m[e] = mh_s[j]; p[e] = prow[512 + j]; bv[e] = bias[512 + j];
        h[e] = h_s[j]; z[e] = z_s[j];
      }
      const float hn2 = hn2_keep;
      float v[3];
      v[0] = 0.f;
      #pragma unroll
      for (int e = 0; e < 8; ++e) v[0] = fmaf(m[e],m[e],v[0]);
      red64N<1>(v);
      const float m2 = v[0];
      const float mn = sqrtf(m2 + EPSF);
      const float s = tanh_fast(mn/xn_rh*artx_rh) * (1.f/mn);
      const float x2 = s*s*m2;
      v[0]=0.f; v[1]=0.f;
      #pragma unroll
      for (int e = 0; e < 8; ++e){ v[0]=fmaf(p[e],p[e],v[0]); v[1]=fmaf(s*m[e],p[e],v[1]); }
      red64N<2>(v);
      float na = 1.f + 2.f*v[1] + v[0];
      float nb = 1.f - x2;
      float rden = 1.f / fmaxf(1.f + 2.f*v[1] + x2*v[0], EPSF);
      #pragma unroll
      for (int e = 0; e < 8; ++e) p[e] = (na*s*m[e] + nb*p[e])*rden;    // q
      v[0]=0.f; v[1]=0.f; v[2]=0.f;
      #pragma unroll
      for (int e = 0; e < 8; ++e){
        v[0]=fmaf(p[e],p[e],v[0]); v[1]=fmaf(bv[e],bv[e],v[1]); v[2]=fmaf(p[e],bv[e],v[2]);
      }
      red64N<3>(v);
      na = 1.f + 2.f*v[2] + v[1];
      nb = 1.f - v[0];
      rden = 1.f / fmaxf(1.f + 2.f*v[2] + v[0]*v[1], EPSF);
      #pragma unroll
      for (int e = 0; e < 8; ++e) m[e] = (na*p[e] + nb*bv[e])*rden;     // ht
      v[0]=0.f; v[1]=0.f;
      #pragma unroll
      for (int e = 0; e < 8; ++e){ v[0]=fmaf(m[e],m[e],v[0]); v[1]=fmaf(h[e],m[e],v[1]); }
      red64N<2>(v);
      {
        const float y2 = v[0], hht = v[1];
        na = 1.f - 2.f*hht + y2;
        nb = 1.f - hn2;
        rden = 1.f / fmaxf(1.f - 2.f*hht + hn2*y2, EPSF);
        #pragma unroll
        for (int e = 0; e < 8; ++e) p[e] = (na*(-h[e]) + nb*m[e])*rden; // delta
      }
      v[0]=0.f; v[1]=0.f; v[2]=0.f;
      #pragma unroll
      for (int e = 0; e < 8; ++e){
        bv[e] = z[e] * p[e];                                            // wz
        v[0] = fmaf(p[e], p[e], v[0]);
        v[1] = fmaf(bv[e], bv[e], v[1]);
        v[2] = fmaf(h[e], bv[e], v[2]);
      }
      red64N<3>(v);
      const float dn  = sqrtf(v[0] + EPSF);
      const float wzn = sqrtf(v[1] + EPSF);
      const float s_pw = tanh_fast(wzn/dn*artanh_fast(dn)) * (1.f/wzn);
      const float y2f = s_pw*s_pw*v[1];
      const float xyf = s_pw*v[2];
      na = 1.f + 2.f*xyf + y2f;
      nb = 1.f - hn2;
      rden = 1.f / fmaxf(1.f + 2.f*xyf + hn2*y2f, EPSF);
      float* outp = outseq + ((size_t)t*Bn + b)*Hn;
      #pragma unroll
      for (int e = 0; e < 8; ++e){
        const int j = l + 64*e;
        const float hn = (na*h[e] + nb*s_pw*bv[e])*rden;
        h_s[j] = hn;
        outp[j] = hn;
        if (t == Tn-1) lastdst[(size_t)b*Hn + j] = hn;
      }
    }
    __syncthreads();   // h_s ready for next step's phase A
  }
}

extern "C" void kernel_launch(void* const* d_in, const int* in_sizes, int n_in,
                              void* d_out, int out_size, void* d_ws, size_t ws_size,
                              hipStream_t stream)
{
  const float* inp  = (const float*)d_in[0];   // (T,B,H)
  const float* Wih  = (const float*)d_in[1];   // (L,3H,H)
  const float* Whh  = (const float*)d_in[2];   // (L,3H,H)
  const float* bias = (const float*)d_in[3];   // (L,3,H)
  float* out  = (float*)d_out;                 // (T,B,H)
  float* last = out + (size_t)Tn*Bn*Hn;        // (L,B,H)

  float* P = (float*)d_ws;                     // CHUNK*Bn x 1536

  for (int l = 0; l < 2; ++l){
    const float* src   = (l == 0) ? inp : out;
    const float* Wihl  = Wih  + (size_t)l*1536*Hn;
    const float* Whhl  = Whh  + (size_t)l*1536*Hn;
    const float* biasl = bias + (size_t)l*3*Hn;
    for (int c = 0; c < Tn/CHUNK; ++c){
      const int t0 = c*CHUNK;
      const float* srcc = src + (size_t)t0*Bn*Hn;
      dim3 gg(CHUNK*Bn/GBM, 1536/GBN);
      hipLaunchKernelGGL(gemm_tn, gg, dim3(256), 0, stream, srcc, Wihl, P);
      hipLaunchKernelGGL(scale_kernel, dim3(CHUNK*Bn), dim3(256), 0, stream,
                         srcc, P);
      const float* hinit = (t0 == 0) ? nullptr
                                     : out + ((size_t)(t0-1))*Bn*Hn;
      hipLaunchKernelGGL(recur_kernel, dim3(Bn), dim3(512), 0, stream,
                         Whhl, biasl, P, hinit,
                         out, last + (size_t)l*Bn*Hn, t0, CHUNK);
    }
  }
}

// Round 11
// 17280.762 us; speedup vs baseline: 1.7052x; 1.7052x over previous
//
#include <hip/hip_runtime.h>
#include <math.h>

#define Tn 256
#define Bn 64
#define Hn 512
#define CHUNK 64
#define EPSF 1e-15f
#define LOG2E 1.4426950408889634f

typedef float f32x2 __attribute__((ext_vector_type(2)));

// ---- hardware transcendentals with series guards ----
__device__ __forceinline__ float exp2_hw(float x){ float r; asm("v_exp_f32 %0, %1" : "=v"(r) : "v"(x)); return r; }
__device__ __forceinline__ float log2_hw(float x){ float r; asm("v_log_f32 %0, %1" : "=v"(r) : "v"(x)); return r; }
__device__ __forceinline__ float rcp_hw (float x){ float r; asm("v_rcp_f32 %0, %1" : "=v"(r) : "v"(x)); return r; }

__device__ __forceinline__ float artanh_fast(float x){   // x >= 0
  const float xc = fminf(x, 1.0f - 1e-7f);
  const float big = 0.34657359028f * (log2_hw(1.f + xc) - log2_hw(1.f - xc));
  const float x2 = x*x;
  const float small = x*(1.f + x2*(0.33333333f + x2*0.2f));
  return (x < 0.01f) ? small : big;
}
__device__ __forceinline__ float tanh_fast(float y){     // y >= 0
  const float t = exp2_hw(-2.f*LOG2E*y);
  const float big = (1.f - t) / (1.f + t);
  const float small = y*(1.f - 0.33333333f*y*y);
  return (y < 0.01f) ? small : big;
}
__device__ __forceinline__ float sigmoid_fast(float x){
  return rcp_hw(1.f + exp2_hw(-LOG2E*x));
}

// full-wave butterfly reduce of N values.
template<int N>
__device__ __forceinline__ void red64N(float* v){
  #pragma unroll
  for (int off = 1; off < 64; off <<= 1){
    #pragma unroll
    for (int n = 0; n < N; ++n) v[n] += __shfl_xor(v[n], off);
  }
}

template<int N>
__device__ __forceinline__ void block_reduceN(float* v, float* red){
  #pragma unroll
  for (int off = 32; off > 0; off >>= 1){
    #pragma unroll
    for (int n = 0; n < N; ++n) v[n] += __shfl_xor(v[n], off);
  }
  const int tid = threadIdx.x;
  const int w = tid >> 6;
  __syncthreads();
  if ((tid & 63) == 0){
    #pragma unroll
    for (int n = 0; n < N; ++n) red[n*4 + w] = v[n];
  }
  __syncthreads();
  #pragma unroll
  for (int n = 0; n < N; ++n)
    v[n] = red[n*4+0] + red[n*4+1] + red[n*4+2] + red[n*4+3];
}

// ---------------- precompute GEMM ------------------------------------------
#define GBM 64
#define GBN 64
#define GBK 16

__global__ __launch_bounds__(256) void gemm_tn(
    const float* __restrict__ A, const float* __restrict__ Bm,
    float* __restrict__ Cm)
{
  __shared__ __align__(16) float As[GBK][GBM];
  __shared__ __align__(16) float Bs[GBK][GBN];
  const int tid = threadIdx.x;
  const int rm0 = blockIdx.x * GBM;
  const int cn0 = blockIdx.y * GBN;
  const int lr = tid >> 2;
  const int lk = (tid & 3) * 4;
  const int tx = tid & 15;
  const int ty = tid >> 4;
  float acc[4][4] = {};
  const float* Arow = A  + (size_t)(rm0 + lr) * 512 + lk;
  const float* Brow = Bm + (size_t)(cn0 + lr) * 512 + lk;
  for (int k0 = 0; k0 < 512; k0 += GBK){
    const float4 av = *reinterpret_cast<const float4*>(Arow + k0);
    const float4 bv = *reinterpret_cast<const float4*>(Brow + k0);
    __syncthreads();
    As[lk+0][lr]=av.x; As[lk+1][lr]=av.y; As[lk+2][lr]=av.z; As[lk+3][lr]=av.w;
    Bs[lk+0][lr]=bv.x; Bs[lk+1][lr]=bv.y; Bs[lk+2][lr]=bv.z; Bs[lk+3][lr]=bv.w;
    __syncthreads();
    #pragma unroll
    for (int kk = 0; kk < GBK; ++kk){
      const float4 a4 = *reinterpret_cast<const float4*>(&As[kk][tx*4]);
      const float4 b4 = *reinterpret_cast<const float4*>(&Bs[kk][ty*4]);
      const float ar[4] = {a4.x, a4.y, a4.z, a4.w};
      const float br[4] = {b4.x, b4.y, b4.z, b4.w};
      #pragma unroll
      for (int i = 0; i < 4; ++i)
        #pragma unroll
        for (int j = 0; j < 4; ++j)
          acc[i][j] = fmaf(ar[i], br[j], acc[i][j]);
    }
  }
  #pragma unroll
  for (int i = 0; i < 4; ++i){
    float4 st; st.x=acc[i][0]; st.y=acc[i][1]; st.z=acc[i][2]; st.w=acc[i][3];
    *reinterpret_cast<float4*>(&Cm[(size_t)(rm0 + tx*4 + i)*1536 + cn0 + ty*4]) = st;
  }
}

// ------- mobius_matvec scaling of P rows ------------------------------------
__global__ __launch_bounds__(256) void scale_kernel(
    const float* __restrict__ src, float* __restrict__ P)
{
  __shared__ float red[24];
  const int row = blockIdx.x, tid = threadIdx.x;
  const float x0 = src[(size_t)row*512 + tid];
  const float x1 = src[(size_t)row*512 + tid + 256];
  float v[3];
  v[0] = x0*x0 + x1*x1; v[1] = 0.f; v[2] = 0.f;
  block_reduceN<3>(v, red);
  const float xn = sqrtf(v[0] + EPSF);
  const float xc = fminf(fmaxf(xn, -1.0f + 1e-7f), 1.0f - 1e-7f);
  const float artx = 0.5f * (log1pf(xc) - log1pf(-xc));
  float* Prow = P + (size_t)row*1536;
  float p[6];
  #pragma unroll
  for (int g = 0; g < 3; ++g){
    p[2*g]   = Prow[g*512 + tid];
    p[2*g+1] = Prow[g*512 + tid + 256];
  }
  float m[3];
  #pragma unroll
  for (int g = 0; g < 3; ++g) m[g] = p[2*g]*p[2*g] + p[2*g+1]*p[2*g+1];
  block_reduceN<3>(m, red);
  #pragma unroll
  for (int g = 0; g < 3; ++g){
    const float mn = sqrtf(m[g] + EPSF);
    const float s = tanhf(mn / xn * artx) / mn;
    Prow[g*512 + tid]       = s * p[2*g];
    Prow[g*512 + tid + 256] = s * p[2*g+1];
  }
}

// ---------------- persistent recurrence: 1 block = 1 batch, no grid sync -----
// 64 blocks x 1024 threads (16 waves). Per step:
//   A: M_r,M_z (1024 rows, 8 passes, row-per-wave loads)  -> LDS
//   chains: wave0 r-chain(+rh) || wave1 z-chain (all-LDS) -> LDS
//   C: M_h (512 rows, 4 passes)                           -> LDS
//   finish: wave0; waves 8-15 prefetch next step's P row  -> LDS (dbuf)
__global__ __launch_bounds__(1024) void recur_kernel(
    const float* __restrict__ Whh,   // (1536,512): [r | hid | z]
    const float* __restrict__ bias,  // (3,512)
    const float* __restrict__ P,     // CHUNK*Bn x 1536 (scaled x-side)
    const float* __restrict__ hinit, // (B,512) previous h, or nullptr -> zeros
    float* __restrict__ outseq,      // (T,B,H)
    float* __restrict__ lastdst,     // (B,H), written at t==Tn-1
    int t0, int nsteps)
{
  __shared__ __align__(16) float h_s[Hn];
  __shared__ __align__(16) float mrz_s[1024];
  __shared__ __align__(16) float mh_s[Hn];
  __shared__ __align__(16) float rh_s[Hn];
  __shared__ __align__(16) float z_s[Hn];
  __shared__ __align__(16) float p_s[2][1536];
  __shared__ __align__(16) float bias_s[1536];
  const int b   = blockIdx.x;
  const int tid = threadIdx.x;
  const int wv  = tid >> 6;     // wave 0..15
  const int l   = tid & 63;     // lane

  for (int j = tid; j < Hn; j += 1024)
    h_s[j] = hinit ? hinit[(size_t)b*Hn + j] : 0.f;
  for (int j = tid; j < 1536; j += 1024){
    bias_s[j] = bias[j];
    p_s[0][j] = P[((size_t)0*Bn + b)*1536 + j];
  }
  __syncthreads();

  float xn_rh = 0.f, artx_rh = 0.f, hn2_keep = 0.f;   // wave-0 step state

  for (int tt = 0; tt < nsteps; ++tt){
    const int t = t0 + tt;
    const int cur = tt & 1;
    const float* ps = p_s[cur];

    // ---------------- A: M_r (rows 0..511) + M_z (rows 512..1023) ----------
    {
      const float4 hA = *reinterpret_cast<const float4*>(&h_s[4*l]);
      const float4 hB = *reinterpret_cast<const float4*>(&h_s[256 + 4*l]);
      #pragma unroll 1
      for (int pass = 0; pass < 8; ++pass){
        const int rowbase = pass*128 + wv*8;
        float acc[8];
        #pragma unroll
        for (int rr = 0; rr < 8; ++rr){
          const int mrow = rowbase + rr;
          const int wrow = (mrow < 512) ? mrow : mrow + 512;
          const float4* wp = reinterpret_cast<const float4*>(Whh + (size_t)wrow*Hn);
          const float4 wa = wp[l];
          const float4 wb = wp[64 + l];
          float a = wa.x*hA.x;
          a = fmaf(wa.y, hA.y, a); a = fmaf(wa.z, hA.z, a); a = fmaf(wa.w, hA.w, a);
          a = fmaf(wb.x, hB.x, a); a = fmaf(wb.y, hB.y, a);
          a = fmaf(wb.z, hB.z, a); a = fmaf(wb.w, hB.w, a);
          acc[rr] = a;
        }
        red64N<8>(acc);
        const float out = (l==0)?acc[0]:(l==1)?acc[1]:(l==2)?acc[2]:(l==3)?acc[3]
                        :(l==4)?acc[4]:(l==5)?acc[5]:(l==6)?acc[6]:acc[7];
        if (l < 8) mrz_s[rowbase + l] = out;
      }
    }
    __syncthreads();

    // ---------------- chains: wave0 = r-chain + rh; wave1 = z-chain --------
    if (wv == 0){
      float m[8], p[8], bv[8], h[8];
      #pragma unroll
      for (int e = 0; e < 8; ++e){
        const int j = l + 64*e;
        m[e] = mrz_s[j]; p[e] = ps[j]; bv[e] = bias_s[j]; h[e] = h_s[j];
      }
      float v[3];
      v[0]=0.f; v[1]=0.f;
      #pragma unroll
      for (int e = 0; e < 8; ++e){ v[0]=fmaf(h[e],h[e],v[0]); v[1]=fmaf(m[e],m[e],v[1]); }
      red64N<2>(v);
      const float hn2 = v[0];
      const float xn_h = sqrtf(hn2 + EPSF);
      const float artx_h = artanh_fast(xn_h);
      const float m2 = v[1];
      const float mn = sqrtf(m2 + EPSF);
      const float s = tanh_fast(mn/xn_h*artx_h) * (1.f/mn);
      const float x2 = s*s*m2;
      v[0]=0.f; v[1]=0.f;
      #pragma unroll
      for (int e = 0; e < 8; ++e){ v[0]=fmaf(p[e],p[e],v[0]); v[1]=fmaf(s*m[e],p[e],v[1]); }
      red64N<2>(v);
      float na = 1.f + 2.f*v[1] + v[0];
      float nb = 1.f - x2;
      float rden = 1.f / fmaxf(1.f + 2.f*v[1] + x2*v[0], EPSF);
      #pragma unroll
      for (int e = 0; e < 8; ++e) p[e] = (na*s*m[e] + nb*p[e])*rden;    // q
      v[0]=0.f; v[1]=0.f; v[2]=0.f;
      #pragma unroll
      for (int e = 0; e < 8; ++e){
        v[0]=fmaf(p[e],p[e],v[0]); v[1]=fmaf(bv[e],bv[e],v[1]); v[2]=fmaf(p[e],bv[e],v[2]);
      }
      red64N<3>(v);
      na = 1.f + 2.f*v[2] + v[1];
      nb = 1.f - v[0];
      rden = 1.f / fmaxf(1.f + 2.f*v[2] + v[0]*v[1], EPSF);
      v[0] = 0.f;
      #pragma unroll
      for (int e = 0; e < 8; ++e){
        m[e] = (na*p[e] + nb*bv[e])*rden;                               // w
        v[0] = fmaf(m[e], m[e], v[0]);
      }
      red64N<1>(v);
      const float yn = sqrtf(v[0] + EPSF);
      const float sc = artanh_fast(yn) * (1.f/yn);
      v[0] = 0.f;
      #pragma unroll
      for (int e = 0; e < 8; ++e){
        const float r = sigmoid_fast(sc*m[e]);
        m[e] = r*h[e];                                                  // u
        v[0] = fmaf(m[e], m[e], v[0]);
      }
      red64N<1>(v);
      const float u2 = v[0];
      const float wn = sqrtf(u2 + EPSF);
      const float s_rh = tanh_fast(wn/xn_h*artx_h) * (1.f/wn);
      #pragma unroll
      for (int e = 0; e < 8; ++e) rh_s[l + 64*e] = s_rh*m[e];
      xn_rh = sqrtf(s_rh*s_rh*u2 + EPSF);
      artx_rh = artanh_fast(xn_rh);
      hn2_keep = hn2;
    } else if (wv == 1){
      float m[8], p[8], bv[8], h[8];
      #pragma unroll
      for (int e = 0; e < 8; ++e){
        const int j = l + 64*e;
        m[e] = mrz_s[512 + j]; p[e] = ps[1024 + j]; bv[e] = bias_s[1024 + j];
        h[e] = h_s[j];
      }
      float v[3];
      v[0]=0.f; v[1]=0.f;
      #pragma unroll
      for (int e = 0; e < 8; ++e){ v[0]=fmaf(h[e],h[e],v[0]); v[1]=fmaf(m[e],m[e],v[1]); }
      red64N<2>(v);
      const float hn2 = v[0];
      const float xn_h = sqrtf(hn2 + EPSF);
      const float artx_h = artanh_fast(xn_h);
      const float m2 = v[1];
      const float mn = sqrtf(m2 + EPSF);
      const float s = tanh_fast(mn/xn_h*artx_h) * (1.f/mn);
      const float x2 = s*s*m2;
      v[0]=0.f; v[1]=0.f;
      #pragma unroll
      for (int e = 0; e < 8; ++e){ v[0]=fmaf(p[e],p[e],v[0]); v[1]=fmaf(s*m[e],p[e],v[1]); }
      red64N<2>(v);
      float na = 1.f + 2.f*v[1] + v[0];
      float nb = 1.f - x2;
      float rden = 1.f / fmaxf(1.f + 2.f*v[1] + x2*v[0], EPSF);
      #pragma unroll
      for (int e = 0; e < 8; ++e) p[e] = (na*s*m[e] + nb*p[e])*rden;    // q
      v[0]=0.f; v[1]=0.f; v[2]=0.f;
      #pragma unroll
      for (int e = 0; e < 8; ++e){
        v[0]=fmaf(p[e],p[e],v[0]); v[1]=fmaf(bv[e],bv[e],v[1]); v[2]=fmaf(p[e],bv[e],v[2]);
      }
      red64N<3>(v);
      na = 1.f + 2.f*v[2] + v[1];
      nb = 1.f - v[0];
      rden = 1.f / fmaxf(1.f + 2.f*v[2] + v[0]*v[1], EPSF);
      float w2[1] = {0.f};
      #pragma unroll
      for (int e = 0; e < 8; ++e){
        m[e] = (na*p[e] + nb*bv[e])*rden;                               // w
        w2[0] = fmaf(m[e], m[e], w2[0]);
      }
      red64N<1>(w2);
      const float yn = sqrtf(w2[0] + EPSF);
      const float sc = artanh_fast(yn) * (1.f/yn);
      #pragma unroll
      for (int e = 0; e < 8; ++e) z_s[l + 64*e] = sigmoid_fast(sc*m[e]);
    }
    __syncthreads();

    // ---------------- C: M_h (W rows 512..1023, operand rh) ----------------
    {
      const float4 rA = *reinterpret_cast<const float4*>(&rh_s[4*l]);
      const float4 rB = *reinterpret_cast<const float4*>(&rh_s[256 + 4*l]);
      #pragma unroll 1
      for (int pass = 0; pass < 4; ++pass){
        const int rowbase = pass*128 + wv*8;
        float acc[8];
        #pragma unroll
        for (int rr = 0; rr < 8; ++rr){
          const float4* wp = reinterpret_cast<const float4*>(
              Whh + (size_t)(512 + rowbase + rr)*Hn);
          const float4 wa = wp[l];
          const float4 wb = wp[64 + l];
          float a = wa.x*rA.x;
          a = fmaf(wa.y, rA.y, a); a = fmaf(wa.z, rA.z, a); a = fmaf(wa.w, rA.w, a);
          a = fmaf(wb.x, rB.x, a); a = fmaf(wb.y, rB.y, a);
          a = fmaf(wb.z, rB.z, a); a = fmaf(wb.w, rB.w, a);
          acc[rr] = a;
        }
        red64N<8>(acc);
        const float out = (l==0)?acc[0]:(l==1)?acc[1]:(l==2)?acc[2]:(l==3)?acc[3]
                        :(l==4)?acc[4]:(l==5)?acc[5]:(l==6)?acc[6]:acc[7];
        if (l < 8) mh_s[rowbase + l] = out;
      }
    }
    __syncthreads();

    // ---------------- finish (wave0) + next-P prefetch (waves 8-15) --------
    if (wv == 0){
      float m[8], p[8], bv[8], h[8], z[8];
      #pragma unroll
      for (int e = 0; e < 8; ++e){
        const int j = l + 64*e;
        m[e] = mh_s[j]; p[e] = ps[512 + j]; bv[e] = bias_s[512 + j];
        h[e] = h_s[j]; z[e] = z_s[j];
      }
      const float hn2 = hn2_keep;
      float v[3];
      v[0] = 0.f;
      #pragma unroll
      for (int e = 0; e < 8; ++e) v[0] = fmaf(m[e],m[e],v[0]);
      red64N<1>(v);
      const float m2 = v[0];
      const float mn = sqrtf(m2 + EPSF);
      const float s = tanh_fast(mn/xn_rh*artx_rh) * (1.f/mn);
      const float x2 = s*s*m2;
      v[0]=0.f; v[1]=0.f;
      #pragma unroll
      for (int e = 0; e < 8; ++e){ v[0]=fmaf(p[e],p[e],v[0]); v[1]=fmaf(s*m[e],p[e],v[1]); }
      red64N<2>(v);
      float na = 1.f + 2.f*v[1] + v[0];
      float nb = 1.f - x2;
      float rden = 1.f / fmaxf(1.f + 2.f*v[1] + x2*v[0], EPSF);
      #pragma unroll
      for (int e = 0; e < 8; ++e) p[e] = (na*s*m[e] + nb*p[e])*rden;    // q
      v[0]=0.f; v[1]=0.f; v[2]=0.f;
      #pragma unroll
      for (int e = 0; e < 8; ++e){
        v[0]=fmaf(p[e],p[e],v[0]); v[1]=fmaf(bv[e],bv[e],v[1]); v[2]=fmaf(p[e],bv[e],v[2]);
      }
      red64N<3>(v);
      na = 1.f + 2.f*v[2] + v[1];
      nb = 1.f - v[0];
      rden = 1.f / fmaxf(1.f + 2.f*v[2] + v[0]*v[1], EPSF);
      #pragma unroll
      for (int e = 0; e < 8; ++e) m[e] = (na*p[e] + nb*bv[e])*rden;     // ht
      v[0]=0.f; v[1]=0.f;
      #pragma unroll
      for (int e = 0; e < 8; ++e){ v[0]=fmaf(m[e],m[e],v[0]); v[1]=fmaf(h[e],m[e],v[1]); }
      red64N<2>(v);
      {
        const float y2 = v[0], hht = v[1];
        na = 1.f - 2.f*hht + y2;
        nb = 1.f - hn2;
        rden = 1.f / fmaxf(1.f - 2.f*hht + hn2*y2, EPSF);
        #pragma unroll
        for (int e = 0; e < 8; ++e) p[e] = (na*(-h[e]) + nb*m[e])*rden; // delta
      }
      v[0]=0.f; v[1]=0.f; v[2]=0.f;
      #pragma unroll
      for (int e = 0; e < 8; ++e){
        bv[e] = z[e] * p[e];                                            // wz
        v[0] = fmaf(p[e], p[e], v[0]);
        v[1] = fmaf(bv[e], bv[e], v[1]);
        v[2] = fmaf(h[e], bv[e], v[2]);
      }
      red64N<3>(v);
      const float dn  = sqrtf(v[0] + EPSF);
      const float wzn = sqrtf(v[1] + EPSF);
      const float s_pw = tanh_fast(wzn/dn*artanh_fast(dn)) * (1.f/wzn);
      const float y2f = s_pw*s_pw*v[1];
      const float xyf = s_pw*v[2];
      na = 1.f + 2.f*xyf + y2f;
      nb = 1.f - hn2;
      rden = 1.f / fmaxf(1.f + 2.f*xyf + hn2*y2f, EPSF);
      float* outp = outseq + ((size_t)t*Bn + b)*Hn;
      #pragma unroll
      for (int e = 0; e < 8; ++e){
        const int j = l + 64*e;
        const float hn = (na*h[e] + nb*s_pw*bv[e])*rden;
        h_s[j] = hn;
        outp[j] = hn;
        if (t == Tn-1) lastdst[(size_t)b*Hn + j] = hn;
      }
    } else if (wv >= 8 && tt + 1 < nsteps){
      const float* pn = P + ((size_t)(tt+1)*Bn + b)*1536;
      for (int j = tid - 512; j < 1536; j += 512)
        p_s[cur ^ 1][j] = pn[j];
    }
    __syncthreads();   // h_s / p_s ready for next step
  }
}

extern "C" void kernel_launch(void* const* d_in, const int* in_sizes, int n_in,
                              void* d_out, int out_size, void* d_ws, size_t ws_size,
                              hipStream_t stream)
{
  const float* inp  = (const float*)d_in[0];   // (T,B,H)
  const float* Wih  = (const float*)d_in[1];   // (L,3H,H)
  const float* Whh  = (const float*)d_in[2];   // (L,3H,H)
  const float* bias = (const float*)d_in[3];   // (L,3,H)
  float* out  = (float*)d_out;                 // (T,B,H)
  float* last = out + (size_t)Tn*Bn*Hn;        // (L,B,H)

  float* P = (float*)d_ws;                     // CHUNK*Bn x 1536

  for (int l = 0; l < 2; ++l){
    const float* src   = (l == 0) ? inp : out;
    const float* Wihl  = Wih  + (size_t)l*1536*Hn;
    const float* Whhl  = Whh  + (size_t)l*1536*Hn;
    const float* biasl = bias + (size_t)l*3*Hn;
    for (int c = 0; c < Tn/CHUNK; ++c){
      const int t0 = c*CHUNK;
      const float* srcc = src + (size_t)t0*Bn*Hn;
      dim3 gg(CHUNK*Bn/GBM, 1536/GBN);
      hipLaunchKernelGGL(gemm_tn, gg, dim3(256), 0, stream, srcc, Wihl, P);
      hipLaunchKernelGGL(scale_kernel, dim3(CHUNK*Bn), dim3(256), 0, stream,
                         srcc, P);
      const float* hinit = (t0 == 0) ? nullptr
                                     : out + ((size_t)(t0-1))*Bn*Hn;
      hipLaunchKernelGGL(recur_kernel, dim3(Bn), dim3(1024), 0, stream,
                         Whhl, biasl, P, hinit,
                         out, last + (size_t)l*Bn*Hn, t0, CHUNK);
    }
  }
}

// Round 13
// 16543.648 us; speedup vs baseline: 1.7811x; 1.0446x over previous
//
#include <hip/hip_runtime.h>
#include <math.h>

#define Tn 256
#define Bn 64
#define Hn 512
#define CHUNK 64
#define EPSF 1e-15f
#define LOG2E 1.4426950408889634f

typedef float f32x2 __attribute__((ext_vector_type(2)));
typedef _Float16 h8 __attribute__((ext_vector_type(8)));

// ---- hardware transcendentals with series guards ----
__device__ __forceinline__ float exp2_hw(float x){ float r; asm("v_exp_f32 %0, %1" : "=v"(r) : "v"(x)); return r; }
__device__ __forceinline__ float log2_hw(float x){ float r; asm("v_log_f32 %0, %1" : "=v"(r) : "v"(x)); return r; }
__device__ __forceinline__ float rcp_hw (float x){ float r; asm("v_rcp_f32 %0, %1" : "=v"(r) : "v"(x)); return r; }

__device__ __forceinline__ float artanh_fast(float x){   // x >= 0
  const float xc = fminf(x, 1.0f - 1e-7f);
  const float big = 0.34657359028f * (log2_hw(1.f + xc) - log2_hw(1.f - xc));
  const float x2 = x*x;
  const float small = x*(1.f + x2*(0.33333333f + x2*0.2f));
  return (x < 0.01f) ? small : big;
}
__device__ __forceinline__ float tanh_fast(float y){     // y >= 0
  const float t = exp2_hw(-2.f*LOG2E*y);
  const float big = (1.f - t) / (1.f + t);
  const float small = y*(1.f - 0.33333333f*y*y);
  return (y < 0.01f) ? small : big;
}
__device__ __forceinline__ float sigmoid_fast(float x){
  return rcp_hw(1.f + exp2_hw(-LOG2E*x));
}

// full-wave butterfly reduce of N values.
template<int N>
__device__ __forceinline__ void red64N(float* v){
  #pragma unroll
  for (int off = 1; off < 64; off <<= 1){
    #pragma unroll
    for (int n = 0; n < N; ++n) v[n] += __shfl_xor(v[n], off);
  }
}

template<int N>
__device__ __forceinline__ void block_reduceN(float* v, float* red){
  #pragma unroll
  for (int off = 32; off > 0; off >>= 1){
    #pragma unroll
    for (int n = 0; n < N; ++n) v[n] += __shfl_xor(v[n], off);
  }
  const int tid = threadIdx.x;
  const int w = tid >> 6;
  __syncthreads();
  if ((tid & 63) == 0){
    #pragma unroll
    for (int n = 0; n < N; ++n) red[n*4 + w] = v[n];
  }
  __syncthreads();
  #pragma unroll
  for (int n = 0; n < N; ++n)
    v[n] = red[n*4+0] + red[n*4+1] + red[n*4+2] + red[n*4+3];
}

// ---------------- W fp32 -> fp16 conversion ---------------------------------
__global__ __launch_bounds__(256) void wconv_kernel(
    const float* __restrict__ W, _Float16* __restrict__ Wh, int n4)
{
  const int i = blockIdx.x*256 + threadIdx.x;
  if (i < n4){
    const float4 v = *reinterpret_cast<const float4*>(W + (size_t)i*4);
    _Float16 h4[4] = {(_Float16)v.x, (_Float16)v.y, (_Float16)v.z, (_Float16)v.w};
    *reinterpret_cast<uint2*>(Wh + (size_t)i*4) = *reinterpret_cast<uint2*>(h4);
  }
}

// ---------------- precompute GEMM ------------------------------------------
#define GBM 64
#define GBN 64
#define GBK 16

__global__ __launch_bounds__(256) void gemm_tn(
    const float* __restrict__ A, const float* __restrict__ Bm,
    float* __restrict__ Cm)
{
  __shared__ __align__(16) float As[GBK][GBM];
  __shared__ __align__(16) float Bs[GBK][GBN];
  const int tid = threadIdx.x;
  const int rm0 = blockIdx.x * GBM;
  const int cn0 = blockIdx.y * GBN;
  const int lr = tid >> 2;
  const int lk = (tid & 3) * 4;
  const int tx = tid & 15;
  const int ty = tid >> 4;
  float acc[4][4] = {};
  const float* Arow = A  + (size_t)(rm0 + lr) * 512 + lk;
  const float* Brow = Bm + (size_t)(cn0 + lr) * 512 + lk;
  for (int k0 = 0; k0 < 512; k0 += GBK){
    const float4 av = *reinterpret_cast<const float4*>(Arow + k0);
    const float4 bv = *reinterpret_cast<const float4*>(Brow + k0);
    __syncthreads();
    As[lk+0][lr]=av.x; As[lk+1][lr]=av.y; As[lk+2][lr]=av.z; As[lk+3][lr]=av.w;
    Bs[lk+0][lr]=bv.x; Bs[lk+1][lr]=bv.y; Bs[lk+2][lr]=bv.z; Bs[lk+3][lr]=bv.w;
    __syncthreads();
    #pragma unroll
    for (int kk = 0; kk < GBK; ++kk){
      const float4 a4 = *reinterpret_cast<const float4*>(&As[kk][tx*4]);
      const float4 b4 = *reinterpret_cast<const float4*>(&Bs[kk][ty*4]);
      const float ar[4] = {a4.x, a4.y, a4.z, a4.w};
      const float br[4] = {b4.x, b4.y, b4.z, b4.w};
      #pragma unroll
      for (int i = 0; i < 4; ++i)
        #pragma unroll
        for (int j = 0; j < 4; ++j)
          acc[i][j] = fmaf(ar[i], br[j], acc[i][j]);
    }
  }
  #pragma unroll
  for (int i = 0; i < 4; ++i){
    float4 st; st.x=acc[i][0]; st.y=acc[i][1]; st.z=acc[i][2]; st.w=acc[i][3];
    *reinterpret_cast<float4*>(&Cm[(size_t)(rm0 + tx*4 + i)*1536 + cn0 + ty*4]) = st;
  }
}

// ------- mobius_matvec scaling of P rows ------------------------------------
__global__ __launch_bounds__(256) void scale_kernel(
    const float* __restrict__ src, float* __restrict__ P)
{
  __shared__ float red[24];
  const int row = blockIdx.x, tid = threadIdx.x;
  const float x0 = src[(size_t)row*512 + tid];
  const float x1 = src[(size_t)row*512 + tid + 256];
  float v[3];
  v[0] = x0*x0 + x1*x1; v[1] = 0.f; v[2] = 0.f;
  block_reduceN<3>(v, red);
  const float xn = sqrtf(v[0] + EPSF);
  const float xc = fminf(fmaxf(xn, -1.0f + 1e-7f), 1.0f - 1e-7f);
  const float artx = 0.5f * (log1pf(xc) - log1pf(-xc));
  float* Prow = P + (size_t)row*1536;
  float p[6];
  #pragma unroll
  for (int g = 0; g < 3; ++g){
    p[2*g]   = Prow[g*512 + tid];
    p[2*g+1] = Prow[g*512 + tid + 256];
  }
  float m[3];
  #pragma unroll
  for (int g = 0; g < 3; ++g) m[g] = p[2*g]*p[2*g] + p[2*g+1]*p[2*g+1];
  block_reduceN<3>(m, red);
  #pragma unroll
  for (int g = 0; g < 3; ++g){
    const float mn = sqrtf(m[g] + EPSF);
    const float s = tanhf(mn / xn * artx) / mn;
    Prow[g*512 + tid]       = s * p[2*g];
    Prow[g*512 + tid + 256] = s * p[2*g+1];
  }
}

// ---------------- persistent recurrence: 1 block = 1 batch, fp16 W ----------
// 64 blocks x 1024 threads (16 waves). Per step:
//   A1: M_r (512 rows, all 16 waves)
//   A2: r-chain (wave0)  ||  M_z (waves 1-15)
//   B : z-chain (wave1)  ||  M_h (waves 0,2-15)
//   finish (wave0)       ||  next-P prefetch (waves 8-15)
__global__ __launch_bounds__(1024) void recur_kernel(
    const _Float16* __restrict__ Wh,  // (1536,512) fp16: [r | hid | z]
    const float* __restrict__ bias,   // (3,512)
    const float* __restrict__ P,      // CHUNK*Bn x 1536 (scaled x-side)
    const float* __restrict__ hinit,  // (B,512) previous h, or nullptr -> zeros
    float* __restrict__ outseq,       // (T,B,H)
    float* __restrict__ lastdst,      // (B,H), written at t==Tn-1
    int t0, int nsteps)
{
  __shared__ __align__(16) float h_s[Hn];
  __shared__ __align__(16) float mrz_s[1024];
  __shared__ __align__(16) float mh_s[Hn];
  __shared__ __align__(16) float rh_s[Hn];
  __shared__ __align__(16) float z_s[Hn];
  __shared__ __align__(16) float p_s[2][1536];
  __shared__ __align__(16) float bias_s[1536];
  const int b   = blockIdx.x;
  const int tid = threadIdx.x;
  const int wv  = tid >> 6;     // wave 0..15
  const int l   = tid & 63;     // lane

  for (int j = tid; j < Hn; j += 1024)
    h_s[j] = hinit ? hinit[(size_t)b*Hn + j] : 0.f;
  for (int j = tid; j < 1536; j += 1024){
    bias_s[j] = bias[j];
    p_s[0][j] = P[(size_t)b*1536 + j];
  }
  __syncthreads();

  float xn_rh = 0.f, artx_rh = 0.f, hn2_keep = 0.f;   // wave-0 step state

  // 8-row fp16 matvec: W rows [rowbase..rowbase+8) dotted with x8 (lane's
  // 8-elem slice of the 512-vector); results -> dstLDS[dstbase + 0..8).
  auto dot8 = [&](const _Float16* Wbase, int rowbase, const float* x8,
                  float* dstLDS, int dstbase){
    float acc[8];
    #pragma unroll
    for (int rr = 0; rr < 8; ++rr){
      const h8* wp = reinterpret_cast<const h8*>(Wbase + (size_t)(rowbase+rr)*Hn);
      const h8 w = wp[l];
      float a0 = 0.f, a1 = 0.f;
      a0 = fmaf((float)w[0], x8[0], a0); a1 = fmaf((float)w[1], x8[1], a1);
      a0 = fmaf((float)w[2], x8[2], a0); a1 = fmaf((float)w[3], x8[3], a1);
      a0 = fmaf((float)w[4], x8[4], a0); a1 = fmaf((float)w[5], x8[5], a1);
      a0 = fmaf((float)w[6], x8[6], a0); a1 = fmaf((float)w[7], x8[7], a1);
      acc[rr] = a0 + a1;
    }
    red64N<8>(acc);
    const float out = (l==0)?acc[0]:(l==1)?acc[1]:(l==2)?acc[2]:(l==3)?acc[3]
                    :(l==4)?acc[4]:(l==5)?acc[5]:(l==6)?acc[6]:acc[7];
    if (l < 8) dstLDS[dstbase + l] = out;
  };

  for (int tt = 0; tt < nsteps; ++tt){
    const int t = t0 + tt;
    const int cur = tt & 1;
    const float* ps = p_s[cur];

    float x8[8];
    #pragma unroll
    for (int e = 0; e < 8; ++e) x8[e] = h_s[8*l + e];

    // ---------------- A1: M_r (rows 0..511), all 16 waves ------------------
    #pragma unroll 1
    for (int pass = 0; pass < 4; ++pass){
      const int rowbase = pass*128 + wv*8;
      dot8(Wh, rowbase, x8, mrz_s, rowbase);
    }
    __syncthreads();

    // ---------------- A2: r-chain (wave0) || M_z (waves 1-15) --------------
    if (wv == 0){
      float m[8], p[8], bv[8], h[8];
      #pragma unroll
      for (int e = 0; e < 8; ++e){
        const int j = l + 64*e;
        m[e] = mrz_s[j]; p[e] = ps[j]; bv[e] = bias_s[j]; h[e] = h_s[j];
      }
      float v[3];
      v[0]=0.f; v[1]=0.f;
      #pragma unroll
      for (int e = 0; e < 8; ++e){ v[0]=fmaf(h[e],h[e],v[0]); v[1]=fmaf(m[e],m[e],v[1]); }
      red64N<2>(v);
      const float hn2 = v[0];
      const float xn_h = sqrtf(hn2 + EPSF);
      const float artx_h = artanh_fast(xn_h);
      const float m2 = v[1];
      const float mn = sqrtf(m2 + EPSF);
      const float s = tanh_fast(mn/xn_h*artx_h) * (1.f/mn);
      const float x2 = s*s*m2;
      v[0]=0.f; v[1]=0.f;
      #pragma unroll
      for (int e = 0; e < 8; ++e){ v[0]=fmaf(p[e],p[e],v[0]); v[1]=fmaf(s*m[e],p[e],v[1]); }
      red64N<2>(v);
      float na = 1.f + 2.f*v[1] + v[0];
      float nb = 1.f - x2;
      float rden = 1.f / fmaxf(1.f + 2.f*v[1] + x2*v[0], EPSF);
      #pragma unroll
      for (int e = 0; e < 8; ++e) p[e] = (na*s*m[e] + nb*p[e])*rden;    // q
      v[0]=0.f; v[1]=0.f; v[2]=0.f;
      #pragma unroll
      for (int e = 0; e < 8; ++e){
        v[0]=fmaf(p[e],p[e],v[0]); v[1]=fmaf(bv[e],bv[e],v[1]); v[2]=fmaf(p[e],bv[e],v[2]);
      }
      red64N<3>(v);
      na = 1.f + 2.f*v[2] + v[1];
      nb = 1.f - v[0];
      rden = 1.f / fmaxf(1.f + 2.f*v[2] + v[0]*v[1], EPSF);
      v[0] = 0.f;
      #pragma unroll
      for (int e = 0; e < 8; ++e){
        m[e] = (na*p[e] + nb*bv[e])*rden;                               // w
        v[0] = fmaf(m[e], m[e], v[0]);
      }
      red64N<1>(v);
      const float yn = sqrtf(v[0] + EPSF);
      const float sc = artanh_fast(yn) * (1.f/yn);
      v[0] = 0.f;
      #pragma unroll
      for (int e = 0; e < 8; ++e){
        const float r = sigmoid_fast(sc*m[e]);
        m[e] = r*h[e];                                                  // u
        v[0] = fmaf(m[e], m[e], v[0]);
      }
      red64N<1>(v);
      const float u2 = v[0];
      const float wn = sqrtf(u2 + EPSF);
      const float s_rh = tanh_fast(wn/xn_h*artx_h) * (1.f/wn);
      #pragma unroll
      for (int e = 0; e < 8; ++e) rh_s[l + 64*e] = s_rh*m[e];
      xn_rh = sqrtf(s_rh*s_rh*u2 + EPSF);
      artx_rh = artanh_fast(xn_rh);
      hn2_keep = hn2;
    } else {
      // M_z: W rows 1024..1535 -> mrz_s[512..1023]; 64 chunks over 15 waves
      #pragma unroll 1
      for (int c = wv - 1; c < 64; c += 15)
        dot8(Wh, 1024 + c*8, x8, mrz_s, 512 + c*8);
    }
    __syncthreads();

    // ---------------- B: z-chain (wave1) || M_h (waves 0,2-15) -------------
    if (wv == 1){
      float m[8], p[8], bv[8], h[8];
      #pragma unroll
      for (int e = 0; e < 8; ++e){
        const int j = l + 64*e;
        m[e] = mrz_s[512 + j]; p[e] = ps[1024 + j]; bv[e] = bias_s[1024 + j];
        h[e] = h_s[j];
      }
      float v[3];
      v[0]=0.f; v[1]=0.f;
      #pragma unroll
      for (int e = 0; e < 8; ++e){ v[0]=fmaf(h[e],h[e],v[0]); v[1]=fmaf(m[e],m[e],v[1]); }
      red64N<2>(v);
      const float hn2 = v[0];
      const float xn_h = sqrtf(hn2 + EPSF);
      const float artx_h = artanh_fast(xn_h);
      const float m2 = v[1];
      const float mn = sqrtf(m2 + EPSF);
      const float s = tanh_fast(mn/xn_h*artx_h) * (1.f/mn);
      const float x2 = s*s*m2;
      v[0]=0.f; v[1]=0.f;
      #pragma unroll
      for (int e = 0; e < 8; ++e){ v[0]=fmaf(p[e],p[e],v[0]); v[1]=fmaf(s*m[e],p[e],v[1]); }
      red64N<2>(v);
      float na = 1.f + 2.f*v[1] + v[0];
      float nb = 1.f - x2;
      float rden = 1.f / fmaxf(1.f + 2.f*v[1] + x2*v[0], EPSF);
      #pragma unroll
      for (int e = 0; e < 8; ++e) p[e] = (na*s*m[e] + nb*p[e])*rden;    // q
      v[0]=0.f; v[1]=0.f; v[2]=0.f;
      #pragma unroll
      for (int e = 0; e < 8; ++e){
        v[0]=fmaf(p[e],p[e],v[0]); v[1]=fmaf(bv[e],bv[e],v[1]); v[2]=fmaf(p[e],bv[e],v[2]);
      }
      red64N<3>(v);
      na = 1.f + 2.f*v[2] + v[1];
      nb = 1.f - v[0];
      rden = 1.f / fmaxf(1.f + 2.f*v[2] + v[0]*v[1], EPSF);
      float w2[1] = {0.f};
      #pragma unroll
      for (int e = 0; e < 8; ++e){
        m[e] = (na*p[e] + nb*bv[e])*rden;                               // w
        w2[0] = fmaf(m[e], m[e], w2[0]);
      }
      red64N<1>(w2);
      const float yn = sqrtf(w2[0] + EPSF);
      const float sc = artanh_fast(yn) * (1.f/yn);
      #pragma unroll
      for (int e = 0; e < 8; ++e) z_s[l + 64*e] = sigmoid_fast(sc*m[e]);
    } else {
      float r8[8];
      #pragma unroll
      for (int e = 0; e < 8; ++e) r8[e] = rh_s[8*l + e];
      const int slot = (wv == 0) ? 0 : wv - 1;   // 15 slots: waves {0,2..15}
      #pragma unroll 1
      for (int c = slot; c < 64; c += 15)
        dot8(Wh, 512 + c*8, r8, mh_s, c*8);
    }
    __syncthreads();

    // ---------------- finish (wave0) || next-P prefetch (waves 8-15) -------
    if (wv == 0){
      float m[8], p[8], bv[8], h[8], z[8];
      #pragma unroll
      for (int e = 0; e < 8; ++e){
        const int j = l + 64*e;
        m[e] = mh_s[j]; p[e] = ps[512 + j]; bv[e] = bias_s[512 + j];
        h[e] = h_s[j]; z[e] = z_s[j];
      }
      const float hn2 = hn2_keep;
      float v[3];
      v[0] = 0.f;
      #pragma unroll
      for (int e = 0; e < 8; ++e) v[0] = fmaf(m[e],m[e],v[0]);
      red64N<1>(v);
      const float m2 = v[0];
      const float mn = sqrtf(m2 + EPSF);
      const float s = tanh_fast(mn/xn_rh*artx_rh) * (1.f/mn);
      const float x2 = s*s*m2;
      v[0]=0.f; v[1]=0.f;
      #pragma unroll
      for (int e = 0; e < 8; ++e){ v[0]=fmaf(p[e],p[e],v[0]); v[1]=fmaf(s*m[e],p[e],v[1]); }
      red64N<2>(v);
      float na = 1.f + 2.f*v[1] + v[0];
      float nb = 1.f - x2;
      float rden = 1.f / fmaxf(1.f + 2.f*v[1] + x2*v[0], EPSF);
      #pragma unroll
      for (int e = 0; e < 8; ++e) p[e] = (na*s*m[e] + nb*p[e])*rden;    // q
      v[0]=0.f; v[1]=0.f; v[2]=0.f;
      #pragma unroll
      for (int e = 0; e < 8; ++e){
        v[0]=fmaf(p[e],p[e],v[0]); v[1]=fmaf(bv[e],bv[e],v[1]); v[2]=fmaf(p[e],bv[e],v[2]);
      }
      red64N<3>(v);
      na = 1.f + 2.f*v[2] + v[1];
      nb = 1.f - v[0];
      rden = 1.f / fmaxf(1.f + 2.f*v[2] + v[0]*v[1], EPSF);
      #pragma unroll
      for (int e = 0; e < 8; ++e) m[e] = (na*p[e] + nb*bv[e])*rden;     // ht
      v[0]=0.f; v[1]=0.f;
      #pragma unroll
      for (int e = 0; e < 8; ++e){ v[0]=fmaf(m[e],m[e],v[0]); v[1]=fmaf(h[e],m[e],v[1]); }
      red64N<2>(v);
      {
        const float y2 = v[0], hht = v[1];
        na = 1.f - 2.f*hht + y2;
        nb = 1.f - hn2;
        rden = 1.f / fmaxf(1.f - 2.f*hht + hn2*y2, EPSF);
        #pragma unroll
        for (int e = 0; e < 8; ++e) p[e] = (na*(-h[e]) + nb*m[e])*rden; // delta
      }
      v[0]=0.f; v[1]=0.f; v[2]=0.f;
      #pragma unroll
      for (int e = 0; e < 8; ++e){
        bv[e] = z[e] * p[e];                                            // wz
        v[0] = fmaf(p[e], p[e], v[0]);
        v[1] = fmaf(bv[e], bv[e], v[1]);
        v[2] = fmaf(h[e], bv[e], v[2]);
      }
      red64N<3>(v);
      const float dn  = sqrtf(v[0] + EPSF);
      const float wzn = sqrtf(v[1] + EPSF);
      const float s_pw = tanh_fast(wzn/dn*artanh_fast(dn)) * (1.f/wzn);
      const float y2f = s_pw*s_pw*v[1];
      const float xyf = s_pw*v[2];
      na = 1.f + 2.f*xyf + y2f;
      nb = 1.f - hn2;
      rden = 1.f / fmaxf(1.f + 2.f*xyf + hn2*y2f, EPSF);
      float* outp = outseq + ((size_t)t*Bn + b)*Hn;
      #pragma unroll
      for (int e = 0; e < 8; ++e){
        const int j = l + 64*e;
        const float hn = (na*h[e] + nb*s_pw*bv[e])*rden;
        h_s[j] = hn;
        outp[j] = hn;
        if (t == Tn-1) lastdst[(size_t)b*Hn + j] = hn;
      }
    } else if (wv >= 8 && tt + 1 < nsteps){
      const float* pn = P + ((size_t)(tt+1)*Bn + b)*1536;
      for (int j = tid - 512; j < 1536; j += 512)
        p_s[cur ^ 1][j] = pn[j];
    }
    __syncthreads();   // h_s / p_s ready for next step
  }
}

extern "C" void kernel_launch(void* const* d_in, const int* in_sizes, int n_in,
                              void* d_out, int out_size, void* d_ws, size_t ws_size,
                              hipStream_t stream)
{
  const float* inp  = (const float*)d_in[0];   // (T,B,H)
  const float* Wih  = (const float*)d_in[1];   // (L,3H,H)
  const float* Whh  = (const float*)d_in[2];   // (L,3H,H)
  const float* bias = (const float*)d_in[3];   // (L,3,H)
  float* out  = (float*)d_out;                 // (T,B,H)
  float* last = out + (size_t)Tn*Bn*Hn;        // (L,B,H)

  float*     P    = (float*)d_ws;                            // CHUNK*Bn x 1536
  _Float16*  Wh16 = (_Float16*)(P + (size_t)CHUNK*Bn*1536);  // 2 x 1536 x 512

  // convert both layers' Whh to fp16 (runs every call: deterministic)
  {
    const int n4 = 2*1536*512/4;
    hipLaunchKernelGGL(wconv_kernel, dim3((n4 + 255)/256), dim3(256), 0, stream,
                       Whh, Wh16, n4);
  }

  for (int l = 0; l < 2; ++l){
    const float* src    = (l == 0) ? inp : out;
    const float* Wihl   = Wih  + (size_t)l*1536*Hn;
    const _Float16* Whl = Wh16 + (size_t)l*1536*Hn;
    const float* biasl  = bias + (size_t)l*3*Hn;
    for (int c = 0; c < Tn/CHUNK; ++c){
      const int t0 = c*CHUNK;
      const float* srcc = src + (size_t)t0*Bn*Hn;
      dim3 gg(CHUNK*Bn/GBM, 1536/GBN);
      hipLaunchKernelGGL(gemm_tn, gg, dim3(256), 0, stream, srcc, Wihl, P);
      hipLaunchKernelGGL(scale_kernel, dim3(CHUNK*Bn), dim3(256), 0, stream,
                         srcc, P);
      const float* hinit = (t0 == 0) ? nullptr
                                     : out + ((size_t)(t0-1))*Bn*Hn;
      hipLaunchKernelGGL(recur_kernel, dim3(Bn), dim3(1024), 0, stream,
                         Whl, biasl, P, hinit,
                         out, last + (size_t)l*Bn*Hn, t0, CHUNK);
    }
  }
}

// Round 14
// 13055.992 us; speedup vs baseline: 2.2569x; 1.2671x over previous
//
#include <hip/hip_runtime.h>
#include <math.h>

#define Tn 256
#define Bn 64
#define Hn 512
#define CHUNK 64
#define EPSF 1e-15f
#define LOG2E 1.4426950408889634f

typedef float f32x2 __attribute__((ext_vector_type(2)));
typedef _Float16 h8 __attribute__((ext_vector_type(8)));

// ---- hardware transcendentals with series guards ----
__device__ __forceinline__ float exp2_hw(float x){ float r; asm("v_exp_f32 %0, %1" : "=v"(r) : "v"(x)); return r; }
__device__ __forceinline__ float log2_hw(float x){ float r; asm("v_log_f32 %0, %1" : "=v"(r) : "v"(x)); return r; }
__device__ __forceinline__ float rcp_hw (float x){ float r; asm("v_rcp_f32 %0, %1" : "=v"(r) : "v"(x)); return r; }

__device__ __forceinline__ float artanh_fast(float x){   // x >= 0
  const float xc = fminf(x, 1.0f - 1e-7f);
  const float big = 0.34657359028f * (log2_hw(1.f + xc) - log2_hw(1.f - xc));
  const float x2 = x*x;
  const float small = x*(1.f + x2*(0.33333333f + x2*0.2f));
  return (x < 0.01f) ? small : big;
}
__device__ __forceinline__ float tanh_fast(float y){     // y >= 0
  const float t = exp2_hw(-2.f*LOG2E*y);
  const float big = (1.f - t) / (1.f + t);
  const float small = y*(1.f - 0.33333333f*y*y);
  return (y < 0.01f) ? small : big;
}
__device__ __forceinline__ float sigmoid_fast(float x){
  return rcp_hw(1.f + exp2_hw(-LOG2E*x));
}

// ---- DPP wave reduction: VALU pipe only (no LDS ops) -----------------------
template<int CTRL, int RM, int BM>
__device__ __forceinline__ float dpp_add(float x){
  union { float f; int i; } u, s;
  u.f = x;
  s.i = __builtin_amdgcn_update_dpp(0, u.i, CTRL, RM, BM, true);
  return x + s.f;
}
// after this, lane 63 holds the 64-lane total (other lanes hold partials)
__device__ __forceinline__ float wave_sum63(float x){
  x = dpp_add<0x111,0xf,0xf>(x);   // row_shr:1
  x = dpp_add<0x112,0xf,0xf>(x);   // row_shr:2
  x = dpp_add<0x114,0xf,0xe>(x);   // row_shr:4
  x = dpp_add<0x118,0xf,0xc>(x);   // row_shr:8
  x = dpp_add<0x142,0xa,0xf>(x);   // row_bcast:15
  x = dpp_add<0x143,0xc,0xf>(x);   // row_bcast:31
  return x;
}
__device__ __forceinline__ float bcast63(float x){
  union { float f; int i; } u; u.f = x;
  u.i = __builtin_amdgcn_readlane(u.i, 63);
  return u.f;
}
// all-lanes wave reduce of N values (VALU only)
template<int N>
__device__ __forceinline__ void red64N(float* v){
  #pragma unroll
  for (int n = 0; n < N; ++n) v[n] = bcast63(wave_sum63(v[n]));
}

template<int N>
__device__ __forceinline__ void block_reduceN(float* v, float* red){
  #pragma unroll
  for (int off = 32; off > 0; off >>= 1){
    #pragma unroll
    for (int n = 0; n < N; ++n) v[n] += __shfl_xor(v[n], off);
  }
  const int tid = threadIdx.x;
  const int w = tid >> 6;
  __syncthreads();
  if ((tid & 63) == 0){
    #pragma unroll
    for (int n = 0; n < N; ++n) red[n*4 + w] = v[n];
  }
  __syncthreads();
  #pragma unroll
  for (int n = 0; n < N; ++n)
    v[n] = red[n*4+0] + red[n*4+1] + red[n*4+2] + red[n*4+3];
}

// ---------------- W fp32 -> fp16 conversion ---------------------------------
__global__ __launch_bounds__(256) void wconv_kernel(
    const float* __restrict__ W, _Float16* __restrict__ Wh, int n4)
{
  const int i = blockIdx.x*256 + threadIdx.x;
  if (i < n4){
    const float4 v = *reinterpret_cast<const float4*>(W + (size_t)i*4);
    _Float16 h4[4] = {(_Float16)v.x, (_Float16)v.y, (_Float16)v.z, (_Float16)v.w};
    *reinterpret_cast<uint2*>(Wh + (size_t)i*4) = *reinterpret_cast<uint2*>(h4);
  }
}

// ---------------- precompute GEMM ------------------------------------------
#define GBM 64
#define GBN 64
#define GBK 16

__global__ __launch_bounds__(256) void gemm_tn(
    const float* __restrict__ A, const float* __restrict__ Bm,
    float* __restrict__ Cm)
{
  __shared__ __align__(16) float As[GBK][GBM];
  __shared__ __align__(16) float Bs[GBK][GBN];
  const int tid = threadIdx.x;
  const int rm0 = blockIdx.x * GBM;
  const int cn0 = blockIdx.y * GBN;
  const int lr = tid >> 2;
  const int lk = (tid & 3) * 4;
  const int tx = tid & 15;
  const int ty = tid >> 4;
  float acc[4][4] = {};
  const float* Arow = A  + (size_t)(rm0 + lr) * 512 + lk;
  const float* Brow = Bm + (size_t)(cn0 + lr) * 512 + lk;
  for (int k0 = 0; k0 < 512; k0 += GBK){
    const float4 av = *reinterpret_cast<const float4*>(Arow + k0);
    const float4 bv = *reinterpret_cast<const float4*>(Brow + k0);
    __syncthreads();
    As[lk+0][lr]=av.x; As[lk+1][lr]=av.y; As[lk+2][lr]=av.z; As[lk+3][lr]=av.w;
    Bs[lk+0][lr]=bv.x; Bs[lk+1][lr]=bv.y; Bs[lk+2][lr]=bv.z; Bs[lk+3][lr]=bv.w;
    __syncthreads();
    #pragma unroll
    for (int kk = 0; kk < GBK; ++kk){
      const float4 a4 = *reinterpret_cast<const float4*>(&As[kk][tx*4]);
      const float4 b4 = *reinterpret_cast<const float4*>(&Bs[kk][ty*4]);
      const float ar[4] = {a4.x, a4.y, a4.z, a4.w};
      const float br[4] = {b4.x, b4.y, b4.z, b4.w};
      #pragma unroll
      for (int i = 0; i < 4; ++i)
        #pragma unroll
        for (int j = 0; j < 4; ++j)
          acc[i][j] = fmaf(ar[i], br[j], acc[i][j]);
    }
  }
  #pragma unroll
  for (int i = 0; i < 4; ++i){
    float4 st; st.x=acc[i][0]; st.y=acc[i][1]; st.z=acc[i][2]; st.w=acc[i][3];
    *reinterpret_cast<float4*>(&Cm[(size_t)(rm0 + tx*4 + i)*1536 + cn0 + ty*4]) = st;
  }
}

// ------- mobius_matvec scaling of P rows ------------------------------------
__global__ __launch_bounds__(256) void scale_kernel(
    const float* __restrict__ src, float* __restrict__ P)
{
  __shared__ float red[24];
  const int row = blockIdx.x, tid = threadIdx.x;
  const float x0 = src[(size_t)row*512 + tid];
  const float x1 = src[(size_t)row*512 + tid + 256];
  float v[3];
  v[0] = x0*x0 + x1*x1; v[1] = 0.f; v[2] = 0.f;
  block_reduceN<3>(v, red);
  const float xn = sqrtf(v[0] + EPSF);
  const float xc = fminf(fmaxf(xn, -1.0f + 1e-7f), 1.0f - 1e-7f);
  const float artx = 0.5f * (log1pf(xc) - log1pf(-xc));
  float* Prow = P + (size_t)row*1536;
  float p[6];
  #pragma unroll
  for (int g = 0; g < 3; ++g){
    p[2*g]   = Prow[g*512 + tid];
    p[2*g+1] = Prow[g*512 + tid + 256];
  }
  float m[3];
  #pragma unroll
  for (int g = 0; g < 3; ++g) m[g] = p[2*g]*p[2*g] + p[2*g+1]*p[2*g+1];
  block_reduceN<3>(m, red);
  #pragma unroll
  for (int g = 0; g < 3; ++g){
    const float mn = sqrtf(m[g] + EPSF);
    const float s = tanhf(mn / xn * artx) / mn;
    Prow[g*512 + tid]       = s * p[2*g];
    Prow[g*512 + tid + 256] = s * p[2*g+1];
  }
}

// ---------------- persistent recurrence: 1 block = 1 batch, fp16 W ----------
// 64 blocks x 1024 threads (16 waves). DPP (VALU-pipe) reductions throughout.
__global__ __launch_bounds__(1024) void recur_kernel(
    const _Float16* __restrict__ Wh,  // (1536,512) fp16: [r | hid | z]
    const float* __restrict__ bias,   // (3,512)
    const float* __restrict__ P,      // CHUNK*Bn x 1536 (scaled x-side)
    const float* __restrict__ hinit,  // (B,512) previous h, or nullptr -> zeros
    float* __restrict__ outseq,       // (T,B,H)
    float* __restrict__ lastdst,      // (B,H), written at t==Tn-1
    int t0, int nsteps)
{
  __shared__ __align__(16) float h_s[Hn];
  __shared__ __align__(16) float mrz_s[1024];
  __shared__ __align__(16) float mh_s[Hn];
  __shared__ __align__(16) float rh_s[Hn];
  __shared__ __align__(16) float z_s[Hn];
  __shared__ __align__(16) float p_s[2][1536];
  __shared__ __align__(16) float bias_s[1536];
  const int b   = blockIdx.x;
  const int tid = threadIdx.x;
  const int wv  = tid >> 6;     // wave 0..15
  const int l   = tid & 63;     // lane

  for (int j = tid; j < Hn; j += 1024)
    h_s[j] = hinit ? hinit[(size_t)b*Hn + j] : 0.f;
  for (int j = tid; j < 1536; j += 1024){
    bias_s[j] = bias[j];
    p_s[0][j] = P[(size_t)b*1536 + j];
  }
  __syncthreads();

  float xn_rh = 0.f, artx_rh = 0.f, hn2_keep = 0.f;   // wave-0 step state

  // 8-row fp16 matvec: W rows [rowbase..rowbase+8) dotted with x8 (lane's
  // 8-elem slice); DPP-reduced; lane 63 stores all 8 results to LDS.
  auto dot8 = [&](const _Float16* Wbase, int rowbase, const float* x8,
                  float* dstLDS, int dstbase){
    float acc[8];
    #pragma unroll
    for (int rr = 0; rr < 8; ++rr){
      const h8* wp = reinterpret_cast<const h8*>(Wbase + (size_t)(rowbase+rr)*Hn);
      const h8 w = wp[l];
      float a0 = 0.f, a1 = 0.f;
      a0 = fmaf((float)w[0], x8[0], a0); a1 = fmaf((float)w[1], x8[1], a1);
      a0 = fmaf((float)w[2], x8[2], a0); a1 = fmaf((float)w[3], x8[3], a1);
      a0 = fmaf((float)w[4], x8[4], a0); a1 = fmaf((float)w[5], x8[5], a1);
      a0 = fmaf((float)w[6], x8[6], a0); a1 = fmaf((float)w[7], x8[7], a1);
      acc[rr] = wave_sum63(a0 + a1);
    }
    if (l == 63){
      #pragma unroll
      for (int rr = 0; rr < 8; ++rr) dstLDS[dstbase + rr] = acc[rr];
    }
  };

  for (int tt = 0; tt < nsteps; ++tt){
    const int t = t0 + tt;
    const int cur = tt & 1;
    const float* ps = p_s[cur];

    float x8[8];
    {
      const float4 a = *reinterpret_cast<const float4*>(&h_s[8*l]);
      const float4 c = *reinterpret_cast<const float4*>(&h_s[8*l + 4]);
      x8[0]=a.x; x8[1]=a.y; x8[2]=a.z; x8[3]=a.w;
      x8[4]=c.x; x8[5]=c.y; x8[6]=c.z; x8[7]=c.w;
    }

    // ---------------- A1: M_r (rows 0..511), all 16 waves ------------------
    #pragma unroll 1
    for (int pass = 0; pass < 4; ++pass){
      const int rowbase = pass*128 + wv*8;
      dot8(Wh, rowbase, x8, mrz_s, rowbase);
    }
    __syncthreads();

    // ---------------- A2: r-chain (wave0) || M_z (waves 1-15) --------------
    if (wv == 0){
      float m[8], p[8], bv[8], h[8];
      #pragma unroll
      for (int e = 0; e < 8; ++e){
        const int j = l + 64*e;
        m[e] = mrz_s[j]; p[e] = ps[j]; bv[e] = bias_s[j]; h[e] = h_s[j];
      }
      float v[3];
      v[0]=0.f; v[1]=0.f;
      #pragma unroll
      for (int e = 0; e < 8; ++e){ v[0]=fmaf(h[e],h[e],v[0]); v[1]=fmaf(m[e],m[e],v[1]); }
      red64N<2>(v);
      const float hn2 = v[0];
      const float xn_h = sqrtf(hn2 + EPSF);
      const float artx_h = artanh_fast(xn_h);
      const float m2 = v[1];
      const float mn = sqrtf(m2 + EPSF);
      const float s = tanh_fast(mn/xn_h*artx_h) * (1.f/mn);
      const float x2 = s*s*m2;
      v[0]=0.f; v[1]=0.f;
      #pragma unroll
      for (int e = 0; e < 8; ++e){ v[0]=fmaf(p[e],p[e],v[0]); v[1]=fmaf(s*m[e],p[e],v[1]); }
      red64N<2>(v);
      float na = 1.f + 2.f*v[1] + v[0];
      float nb = 1.f - x2;
      float rden = 1.f / fmaxf(1.f + 2.f*v[1] + x2*v[0], EPSF);
      #pragma unroll
      for (int e = 0; e < 8; ++e) p[e] = (na*s*m[e] + nb*p[e])*rden;    // q
      v[0]=0.f; v[1]=0.f; v[2]=0.f;
      #pragma unroll
      for (int e = 0; e < 8; ++e){
        v[0]=fmaf(p[e],p[e],v[0]); v[1]=fmaf(bv[e],bv[e],v[1]); v[2]=fmaf(p[e],bv[e],v[2]);
      }
      red64N<3>(v);
      na = 1.f + 2.f*v[2] + v[1];
      nb = 1.f - v[0];
      rden = 1.f / fmaxf(1.f + 2.f*v[2] + v[0]*v[1], EPSF);
      v[0] = 0.f;
      #pragma unroll
      for (int e = 0; e < 8; ++e){
        m[e] = (na*p[e] + nb*bv[e])*rden;                               // w
        v[0] = fmaf(m[e], m[e], v[0]);
      }
      red64N<1>(v);
      const float yn = sqrtf(v[0] + EPSF);
      const float sc = artanh_fast(yn) * (1.f/yn);
      v[0] = 0.f;
      #pragma unroll
      for (int e = 0; e < 8; ++e){
        const float r = sigmoid_fast(sc*m[e]);
        m[e] = r*h[e];                                                  // u
        v[0] = fmaf(m[e], m[e], v[0]);
      }
      red64N<1>(v);
      const float u2 = v[0];
      const float wn = sqrtf(u2 + EPSF);
      const float s_rh = tanh_fast(wn/xn_h*artx_h) * (1.f/wn);
      #pragma unroll
      for (int e = 0; e < 8; ++e) rh_s[l + 64*e] = s_rh*m[e];
      xn_rh = sqrtf(s_rh*s_rh*u2 + EPSF);
      artx_rh = artanh_fast(xn_rh);
      hn2_keep = hn2;
    } else {
      // M_z: W rows 1024..1535 -> mrz_s[512..1023]; 64 chunks over 15 waves
      #pragma unroll 1
      for (int c = wv - 1; c < 64; c += 15)
        dot8(Wh, 1024 + c*8, x8, mrz_s, 512 + c*8);
    }
    __syncthreads();

    // ---------------- B: z-chain (wave1) || M_h (waves 0,2-15) -------------
    if (wv == 1){
      float m[8], p[8], bv[8], h[8];
      #pragma unroll
      for (int e = 0; e < 8; ++e){
        const int j = l + 64*e;
        m[e] = mrz_s[512 + j]; p[e] = ps[1024 + j]; bv[e] = bias_s[1024 + j];
        h[e] = h_s[j];
      }
      float v[3];
      v[0]=0.f; v[1]=0.f;
      #pragma unroll
      for (int e = 0; e < 8; ++e){ v[0]=fmaf(h[e],h[e],v[0]); v[1]=fmaf(m[e],m[e],v[1]); }
      red64N<2>(v);
      const float hn2 = v[0];
      const float xn_h = sqrtf(hn2 + EPSF);
      const float artx_h = artanh_fast(xn_h);
      const float m2 = v[1];
      const float mn = sqrtf(m2 + EPSF);
      const float s = tanh_fast(mn/xn_h*artx_h) * (1.f/mn);
      const float x2 = s*s*m2;
      v[0]=0.f; v[1]=0.f;
      #pragma unroll
      for (int e = 0; e < 8; ++e){ v[0]=fmaf(p[e],p[e],v[0]); v[1]=fmaf(s*m[e],p[e],v[1]); }
      red64N<2>(v);
      float na = 1.f + 2.f*v[1] + v[0];
      float nb = 1.f - x2;
      float rden = 1.f / fmaxf(1.f + 2.f*v[1] + x2*v[0], EPSF);
      #pragma unroll
      for (int e = 0; e < 8; ++e) p[e] = (na*s*m[e] + nb*p[e])*rden;    // q
      v[0]=0.f; v[1]=0.f; v[2]=0.f;
      #pragma unroll
      for (int e = 0; e < 8; ++e){
        v[0]=fmaf(p[e],p[e],v[0]); v[1]=fmaf(bv[e],bv[e],v[1]); v[2]=fmaf(p[e],bv[e],v[2]);
      }
      red64N<3>(v);
      na = 1.f + 2.f*v[2] + v[1];
      nb = 1.f - v[0];
      rden = 1.f / fmaxf(1.f + 2.f*v[2] + v[0]*v[1], EPSF);
      float w2[1] = {0.f};
      #pragma unroll
      for (int e = 0; e < 8; ++e){
        m[e] = (na*p[e] + nb*bv[e])*rden;                               // w
        w2[0] = fmaf(m[e], m[e], w2[0]);
      }
      red64N<1>(w2);
      const float yn = sqrtf(w2[0] + EPSF);
      const float sc = artanh_fast(yn) * (1.f/yn);
      #pragma unroll
      for (int e = 0; e < 8; ++e) z_s[l + 64*e] = sigmoid_fast(sc*m[e]);
    } else {
      float r8[8];
      {
        const float4 a = *reinterpret_cast<const float4*>(&rh_s[8*l]);
        const float4 c = *reinterpret_cast<const float4*>(&rh_s[8*l + 4]);
        r8[0]=a.x; r8[1]=a.y; r8[2]=a.z; r8[3]=a.w;
        r8[4]=c.x; r8[5]=c.y; r8[6]=c.z; r8[7]=c.w;
      }
      const int slot = (wv == 0) ? 0 : wv - 1;   // 15 slots: waves {0,2..15}
      #pragma unroll 1
      for (int c = slot; c < 64; c += 15)
        dot8(Wh, 512 + c*8, r8, mh_s, c*8);
    }
    __syncthreads();

    // ---------------- finish (wave0) || next-P prefetch (waves 8-15) -------
    if (wv == 0){
      float m[8], p[8], bv[8], h[8], z[8];
      #pragma unroll
      for (int e = 0; e < 8; ++e){
        const int j = l + 64*e;
        m[e] = mh_s[j]; p[e] = ps[512 + j]; bv[e] = bias_s[512 + j];
        h[e] = h_s[j]; z[e] = z_s[j];
      }
      const float hn2 = hn2_keep;
      float v[3];
      v[0] = 0.f;
      #pragma unroll
      for (int e = 0; e < 8; ++e) v[0] = fmaf(m[e],m[e],v[0]);
      red64N<1>(v);
      const float m2 = v[0];
      const float mn = sqrtf(m2 + EPSF);
      const float s = tanh_fast(mn/xn_rh*artx_rh) * (1.f/mn);
      const float x2 = s*s*m2;
      v[0]=0.f; v[1]=0.f;
      #pragma unroll
      for (int e = 0; e < 8; ++e){ v[0]=fmaf(p[e],p[e],v[0]); v[1]=fmaf(s*m[e],p[e],v[1]); }
      red64N<2>(v);
      float na = 1.f + 2.f*v[1] + v[0];
      float nb = 1.f - x2;
      float rden = 1.f / fmaxf(1.f + 2.f*v[1] + x2*v[0], EPSF);
      #pragma unroll
      for (int e = 0; e < 8; ++e) p[e] = (na*s*m[e] + nb*p[e])*rden;    // q
      v[0]=0.f; v[1]=0.f; v[2]=0.f;
      #pragma unroll
      for (int e = 0; e < 8; ++e){
        v[0]=fmaf(p[e],p[e],v[0]); v[1]=fmaf(bv[e],bv[e],v[1]); v[2]=fmaf(p[e],bv[e],v[2]);
      }
      red64N<3>(v);
      na = 1.f + 2.f*v[2] + v[1];
      nb = 1.f - v[0];
      rden = 1.f / fmaxf(1.f + 2.f*v[2] + v[0]*v[1], EPSF);
      #pragma unroll
      for (int e = 0; e < 8; ++e) m[e] = (na*p[e] + nb*bv[e])*rden;     // ht
      v[0]=0.f; v[1]=0.f;
      #pragma unroll
      for (int e = 0; e < 8; ++e){ v[0]=fmaf(m[e],m[e],v[0]); v[1]=fmaf(h[e],m[e],v[1]); }
      red64N<2>(v);
      {
        const float y2 = v[0], hht = v[1];
        na = 1.f - 2.f*hht + y2;
        nb = 1.f - hn2;
        rden = 1.f / fmaxf(1.f - 2.f*hht + hn2*y2, EPSF);
        #pragma unroll
        for (int e = 0; e < 8; ++e) p[e] = (na*(-h[e]) + nb*m[e])*rden; // delta
      }
      v[0]=0.f; v[1]=0.f; v[2]=0.f;
      #pragma unroll
      for (int e = 0; e < 8; ++e){
        bv[e] = z[e] * p[e];                                            // wz
        v[0] = fmaf(p[e], p[e], v[0]);
        v[1] = fmaf(bv[e], bv[e], v[1]);
        v[2] = fmaf(h[e], bv[e], v[2]);
      }
      red64N<3>(v);
      const float dn  = sqrtf(v[0] + EPSF);
      const float wzn = sqrtf(v[1] + EPSF);
      const float s_pw = tanh_fast(wzn/dn*artanh_fast(dn)) * (1.f/wzn);
      const float y2f = s_pw*s_pw*v[1];
      const float xyf = s_pw*v[2];
      na = 1.f + 2.f*xyf + y2f;
      nb = 1.f - hn2;
      rden = 1.f / fmaxf(1.f + 2.f*xyf + hn2*y2f, EPSF);
      float* outp = outseq + ((size_t)t*Bn + b)*Hn;
      #pragma unroll
      for (int e = 0; e < 8; ++e){
        const int j = l + 64*e;
        const float hn = (na*h[e] + nb*s_pw*bv[e])*rden;
        h_s[j] = hn;
        outp[j] = hn;
        if (t == Tn-1) lastdst[(size_t)b*Hn + j] = hn;
      }
    } else if (wv >= 8 && tt + 1 < nsteps){
      const float* pn = P + ((size_t)(tt+1)*Bn + b)*1536;
      for (int j = tid - 512; j < 1536; j += 512)
        p_s[cur ^ 1][j] = pn[j];
    }
    __syncthreads();   // h_s / p_s ready for next step
  }
}

extern "C" void kernel_launch(void* const* d_in, const int* in_sizes, int n_in,
                              void* d_out, int out_size, void* d_ws, size_t ws_size,
                              hipStream_t stream)
{
  const float* inp  = (const float*)d_in[0];   // (T,B,H)
  const float* Wih  = (const float*)d_in[1];   // (L,3H,H)
  const float* Whh  = (const float*)d_in[2];   // (L,3H,H)
  const float* bias = (const float*)d_in[3];   // (L,3,H)
  float* out  = (float*)d_out;                 // (T,B,H)
  float* last = out + (size_t)Tn*Bn*Hn;        // (L,B,H)

  float*     P    = (float*)d_ws;                            // CHUNK*Bn x 1536
  _Float16*  Wh16 = (_Float16*)(P + (size_t)CHUNK*Bn*1536);  // 2 x 1536 x 512

  // convert both layers' Whh to fp16 (runs every call: deterministic)
  {
    const int n4 = 2*1536*512/4;
    hipLaunchKernelGGL(wconv_kernel, dim3((n4 + 255)/256), dim3(256), 0, stream,
                       Whh, Wh16, n4);
  }

  for (int l = 0; l < 2; ++l){
    const float* src    = (l == 0) ? inp : out;
    const float* Wihl   = Wih  + (size_t)l*1536*Hn;
    const _Float16* Whl = Wh16 + (size_t)l*1536*Hn;
    const float* biasl  = bias + (size_t)l*3*Hn;
    for (int c = 0; c < Tn/CHUNK; ++c){
      const int t0 = c*CHUNK;
      const float* srcc = src + (size_t)t0*Bn*Hn;
      dim3 gg(CHUNK*Bn/GBM, 1536/GBN);
      hipLaunchKernelGGL(gemm_tn, gg, dim3(256), 0, stream, srcc, Wihl, P);
      hipLaunchKernelGGL(scale_kernel, dim3(CHUNK*Bn), dim3(256), 0, stream,
                         srcc, P);
      const float* hinit = (t0 == 0) ? nullptr
                                     : out + ((size_t)(t0-1))*Bn*Hn;
      hipLaunchKernelGGL(recur_kernel, dim3(Bn), dim3(1024), 0, stream,
                         Whl, biasl, P, hinit,
                         out, last + (size_t)l*Bn*Hn, t0, CHUNK);
    }
  }
}

// Round 15
// 9138.124 us; speedup vs baseline: 3.2246x; 1.4287x over previous
//
#include <hip/hip_runtime.h>
#include <math.h>

#define Tn 256
#define Bn 64
#define Hn 512
#define CHUNK 64
#define EPSF 1e-15f
#define LOG2E 1.4426950408889634f

typedef float f32x2 __attribute__((ext_vector_type(2)));
typedef _Float16 h8 __attribute__((ext_vector_type(8)));
typedef _Float16 half2 __attribute__((ext_vector_type(2)));

// ---- hardware transcendentals with series guards ----
__device__ __forceinline__ float exp2_hw(float x){ float r; asm("v_exp_f32 %0, %1" : "=v"(r) : "v"(x)); return r; }
__device__ __forceinline__ float log2_hw(float x){ float r; asm("v_log_f32 %0, %1" : "=v"(r) : "v"(x)); return r; }
__device__ __forceinline__ float rcp_hw (float x){ float r; asm("v_rcp_f32 %0, %1" : "=v"(r) : "v"(x)); return r; }

__device__ __forceinline__ float artanh_fast(float x){   // x >= 0
  const float xc = fminf(x, 1.0f - 1e-7f);
  const float big = 0.34657359028f * (log2_hw(1.f + xc) - log2_hw(1.f - xc));
  const float x2 = x*x;
  const float small = x*(1.f + x2*(0.33333333f + x2*0.2f));
  return (x < 0.01f) ? small : big;
}
__device__ __forceinline__ float tanh_fast(float y){     // y >= 0
  const float t = exp2_hw(-2.f*LOG2E*y);
  const float big = (1.f - t) / (1.f + t);
  const float small = y*(1.f - 0.33333333f*y*y);
  return (y < 0.01f) ? small : big;
}
__device__ __forceinline__ float sigmoid_fast(float x){
  return rcp_hw(1.f + exp2_hw(-LOG2E*x));
}

// fp16 pair dot with f32 accumulate
__device__ __forceinline__ float fdot2(half2 a, half2 b, float c){
#if __has_builtin(__builtin_amdgcn_fdot2)
  return __builtin_amdgcn_fdot2(a, b, c, false);
#else
  c = fmaf((float)a[0], (float)b[0], c);
  return fmaf((float)a[1], (float)b[1], c);
#endif
}

// ---- DPP wave reduction: VALU pipe only ----
template<int CTRL, int RM, int BM>
__device__ __forceinline__ float dpp_add(float x){
  union { float f; int i; } u, s;
  u.f = x;
  s.i = __builtin_amdgcn_update_dpp(0, u.i, CTRL, RM, BM, true);
  return x + s.f;
}
__device__ __forceinline__ float wave_sum63(float x){
  x = dpp_add<0x111,0xf,0xf>(x);   // row_shr:1
  x = dpp_add<0x112,0xf,0xf>(x);   // row_shr:2
  x = dpp_add<0x114,0xf,0xe>(x);   // row_shr:4
  x = dpp_add<0x118,0xf,0xc>(x);   // row_shr:8
  x = dpp_add<0x142,0xa,0xf>(x);   // row_bcast:15
  x = dpp_add<0x143,0xc,0xf>(x);   // row_bcast:31
  return x;
}
__device__ __forceinline__ float bcast63(float x){
  union { float f; int i; } u; u.f = x;
  u.i = __builtin_amdgcn_readlane(u.i, 63);
  return u.f;
}
template<int N>
__device__ __forceinline__ void red64N(float* v){
  #pragma unroll
  for (int n = 0; n < N; ++n) v[n] = bcast63(wave_sum63(v[n]));
}

template<int N>
__device__ __forceinline__ void block_reduceN(float* v, float* red){
  #pragma unroll
  for (int off = 32; off > 0; off >>= 1){
    #pragma unroll
    for (int n = 0; n < N; ++n) v[n] += __shfl_xor(v[n], off);
  }
  const int tid = threadIdx.x;
  const int w = tid >> 6;
  __syncthreads();
  if ((tid & 63) == 0){
    #pragma unroll
    for (int n = 0; n < N; ++n) red[n*4 + w] = v[n];
  }
  __syncthreads();
  #pragma unroll
  for (int n = 0; n < N; ++n)
    v[n] = red[n*4+0] + red[n*4+1] + red[n*4+2] + red[n*4+3];
}

// ---------------- W fp32 -> fp16 conversion ---------------------------------
__global__ __launch_bounds__(256) void wconv_kernel(
    const float* __restrict__ W, _Float16* __restrict__ Wh, int n4)
{
  const int i = blockIdx.x*256 + threadIdx.x;
  if (i < n4){
    const float4 v = *reinterpret_cast<const float4*>(W + (size_t)i*4);
    _Float16 h4[4] = {(_Float16)v.x, (_Float16)v.y, (_Float16)v.z, (_Float16)v.w};
    *reinterpret_cast<uint2*>(Wh + (size_t)i*4) = *reinterpret_cast<uint2*>(h4);
  }
}

// ---------------- precompute GEMM ------------------------------------------
#define GBM 64
#define GBN 64
#define GBK 16

__global__ __launch_bounds__(256) void gemm_tn(
    const float* __restrict__ A, const float* __restrict__ Bm,
    float* __restrict__ Cm)
{
  __shared__ __align__(16) float As[GBK][GBM];
  __shared__ __align__(16) float Bs[GBK][GBN];
  const int tid = threadIdx.x;
  const int rm0 = blockIdx.x * GBM;
  const int cn0 = blockIdx.y * GBN;
  const int lr = tid >> 2;
  const int lk = (tid & 3) * 4;
  const int tx = tid & 15;
  const int ty = tid >> 4;
  float acc[4][4] = {};
  const float* Arow = A  + (size_t)(rm0 + lr) * 512 + lk;
  const float* Brow = Bm + (size_t)(cn0 + lr) * 512 + lk;
  for (int k0 = 0; k0 < 512; k0 += GBK){
    const float4 av = *reinterpret_cast<const float4*>(Arow + k0);
    const float4 bv = *reinterpret_cast<const float4*>(Brow + k0);
    __syncthreads();
    As[lk+0][lr]=av.x; As[lk+1][lr]=av.y; As[lk+2][lr]=av.z; As[lk+3][lr]=av.w;
    Bs[lk+0][lr]=bv.x; Bs[lk+1][lr]=bv.y; Bs[lk+2][lr]=bv.z; Bs[lk+3][lr]=bv.w;
    __syncthreads();
    #pragma unroll
    for (int kk = 0; kk < GBK; ++kk){
      const float4 a4 = *reinterpret_cast<const float4*>(&As[kk][tx*4]);
      const float4 b4 = *reinterpret_cast<const float4*>(&Bs[kk][ty*4]);
      const float ar[4] = {a4.x, a4.y, a4.z, a4.w};
      const float br[4] = {b4.x, b4.y, b4.z, b4.w};
      #pragma unroll
      for (int i = 0; i < 4; ++i)
        #pragma unroll
        for (int j = 0; j < 4; ++j)
          acc[i][j] = fmaf(ar[i], br[j], acc[i][j]);
    }
  }
  #pragma unroll
  for (int i = 0; i < 4; ++i){
    float4 st; st.x=acc[i][0]; st.y=acc[i][1]; st.z=acc[i][2]; st.w=acc[i][3];
    *reinterpret_cast<float4*>(&Cm[(size_t)(rm0 + tx*4 + i)*1536 + cn0 + ty*4]) = st;
  }
}

// ------- mobius_matvec scaling of P rows ------------------------------------
__global__ __launch_bounds__(256) void scale_kernel(
    const float* __restrict__ src, float* __restrict__ P)
{
  __shared__ float red[24];
  const int row = blockIdx.x, tid = threadIdx.x;
  const float x0 = src[(size_t)row*512 + tid];
  const float x1 = src[(size_t)row*512 + tid + 256];
  float v[3];
  v[0] = x0*x0 + x1*x1; v[1] = 0.f; v[2] = 0.f;
  block_reduceN<3>(v, red);
  const float xn = sqrtf(v[0] + EPSF);
  const float xc = fminf(fmaxf(xn, -1.0f + 1e-7f), 1.0f - 1e-7f);
  const float artx = 0.5f * (log1pf(xc) - log1pf(-xc));
  float* Prow = P + (size_t)row*1536;
  float p[6];
  #pragma unroll
  for (int g = 0; g < 3; ++g){
    p[2*g]   = Prow[g*512 + tid];
    p[2*g+1] = Prow[g*512 + tid + 256];
  }
  float m[3];
  #pragma unroll
  for (int g = 0; g < 3; ++g) m[g] = p[2*g]*p[2*g] + p[2*g+1]*p[2*g+1];
  block_reduceN<3>(m, red);
  #pragma unroll
  for (int g = 0; g < 3; ++g){
    const float mn = sqrtf(m[g] + EPSF);
    const float s = tanhf(mn / xn * artx) / mn;
    Prow[g*512 + tid]       = s * p[2*g];
    Prow[g*512 + tid + 256] = s * p[2*g+1];
  }
}

// ---------------- persistent recurrence: 1 block = 1 batch, fp16 W + fdot2 ---
__global__ __launch_bounds__(1024) void recur_kernel(
    const _Float16* __restrict__ Wh,  // (1536,512) fp16: [r | hid | z]
    const float* __restrict__ bias,   // (3,512)
    const float* __restrict__ P,      // CHUNK*Bn x 1536 (scaled x-side)
    const float* __restrict__ hinit,  // (B,512) previous h, or nullptr -> zeros
    float* __restrict__ outseq,       // (T,B,H)
    float* __restrict__ lastdst,      // (B,H), written at t==Tn-1
    int t0, int nsteps)
{
  __shared__ __align__(16) float h_s[Hn];
  __shared__ __align__(16) _Float16 h16_s[Hn];
  __shared__ __align__(16) _Float16 rh16_s[Hn];
  __shared__ __align__(16) float mrz_s[1024];
  __shared__ __align__(16) float mh_s[Hn];
  __shared__ __align__(16) float z_s[Hn];
  __shared__ __align__(16) float p_s[2][1536];
  __shared__ __align__(16) float bias_s[1536];
  const int b   = blockIdx.x;
  const int tid = threadIdx.x;
  const int wv  = tid >> 6;     // wave 0..15
  const int l   = tid & 63;     // lane

  for (int j = tid; j < Hn; j += 1024){
    const float hv = hinit ? hinit[(size_t)b*Hn + j] : 0.f;
    h_s[j] = hv;
    h16_s[j] = (_Float16)hv;
  }
  for (int j = tid; j < 1536; j += 1024){
    bias_s[j] = bias[j];
    p_s[0][j] = P[(size_t)b*1536 + j];
  }
  __syncthreads();

  float xn_rh = 0.f, artx_rh = 0.f, hn2_keep = 0.f;   // wave-0 step state

  // 8-row fp16 matvec with v_dot2_f32_f16; loads batched before reduce.
  auto dot8 = [&](const _Float16* Wbase, int rowbase, const h8 xv,
                  float* dstLDS, int dstbase){
    h8 w[8];
    #pragma unroll
    for (int rr = 0; rr < 8; ++rr)
      w[rr] = reinterpret_cast<const h8*>(Wbase + (size_t)(rowbase+rr)*Hn)[l];
    const half2* xp = reinterpret_cast<const half2*>(&xv);
    float acc[8];
    #pragma unroll
    for (int rr = 0; rr < 8; ++rr){
      const half2* wp2 = reinterpret_cast<const half2*>(&w[rr]);
      float a = 0.f;
      a = fdot2(wp2[0], xp[0], a);
      a = fdot2(wp2[1], xp[1], a);
      a = fdot2(wp2[2], xp[2], a);
      a = fdot2(wp2[3], xp[3], a);
      acc[rr] = wave_sum63(a);
    }
    if (l == 63){
      #pragma unroll
      for (int rr = 0; rr < 8; ++rr) dstLDS[dstbase + rr] = acc[rr];
    }
  };

  for (int tt = 0; tt < nsteps; ++tt){
    const int t = t0 + tt;
    const int cur = tt & 1;
    const float* ps = p_s[cur];

    const h8 xv = *reinterpret_cast<const h8*>(&h16_s[8*l]);

    // ---------------- A1: M_r (rows 0..511), all 16 waves ------------------
    #pragma unroll 1
    for (int pass = 0; pass < 4; ++pass){
      const int rowbase = pass*128 + wv*8;
      dot8(Wh, rowbase, xv, mrz_s, rowbase);
    }
    __syncthreads();

    // ---------------- A2: r-chain (wave0) || M_z (waves 1-15) --------------
    if (wv == 0){
      float m[8], p[8], bv[8], h[8];
      #pragma unroll
      for (int e = 0; e < 8; ++e){
        const int j = l + 64*e;
        m[e] = mrz_s[j]; p[e] = ps[j]; bv[e] = bias_s[j]; h[e] = h_s[j];
      }
      float v[3];
      v[0]=0.f; v[1]=0.f;
      #pragma unroll
      for (int e = 0; e < 8; ++e){ v[0]=fmaf(h[e],h[e],v[0]); v[1]=fmaf(m[e],m[e],v[1]); }
      red64N<2>(v);
      const float hn2 = v[0];
      const float xn_h = sqrtf(hn2 + EPSF);
      const float artx_h = artanh_fast(xn_h);
      const float m2 = v[1];
      const float mn = sqrtf(m2 + EPSF);
      const float s = tanh_fast(mn/xn_h*artx_h) * (1.f/mn);
      const float x2 = s*s*m2;
      v[0]=0.f; v[1]=0.f;
      #pragma unroll
      for (int e = 0; e < 8; ++e){ v[0]=fmaf(p[e],p[e],v[0]); v[1]=fmaf(s*m[e],p[e],v[1]); }
      red64N<2>(v);
      float na = 1.f + 2.f*v[1] + v[0];
      float nb = 1.f - x2;
      float rden = 1.f / fmaxf(1.f + 2.f*v[1] + x2*v[0], EPSF);
      #pragma unroll
      for (int e = 0; e < 8; ++e) p[e] = (na*s*m[e] + nb*p[e])*rden;    // q
      v[0]=0.f; v[1]=0.f; v[2]=0.f;
      #pragma unroll
      for (int e = 0; e < 8; ++e){
        v[0]=fmaf(p[e],p[e],v[0]); v[1]=fmaf(bv[e],bv[e],v[1]); v[2]=fmaf(p[e],bv[e],v[2]);
      }
      red64N<3>(v);
      na = 1.f + 2.f*v[2] + v[1];
      nb = 1.f - v[0];
      rden = 1.f / fmaxf(1.f + 2.f*v[2] + v[0]*v[1], EPSF);
      v[0] = 0.f;
      #pragma unroll
      for (int e = 0; e < 8; ++e){
        m[e] = (na*p[e] + nb*bv[e])*rden;                               // w
        v[0] = fmaf(m[e], m[e], v[0]);
      }
      red64N<1>(v);
      const float yn = sqrtf(v[0] + EPSF);
      const float sc = artanh_fast(yn) * (1.f/yn);
      v[0] = 0.f;
      #pragma unroll
      for (int e = 0; e < 8; ++e){
        const float r = sigmoid_fast(sc*m[e]);
        m[e] = r*h[e];                                                  // u
        v[0] = fmaf(m[e], m[e], v[0]);
      }
      red64N<1>(v);
      const float u2 = v[0];
      const float wn = sqrtf(u2 + EPSF);
      const float s_rh = tanh_fast(wn/xn_h*artx_h) * (1.f/wn);
      #pragma unroll
      for (int e = 0; e < 8; ++e) rh16_s[l + 64*e] = (_Float16)(s_rh*m[e]);
      xn_rh = sqrtf(s_rh*s_rh*u2 + EPSF);
      artx_rh = artanh_fast(xn_rh);
      hn2_keep = hn2;
    } else {
      // M_z: W rows 1024..1535 -> mrz_s[512..1023]; 64 chunks over 15 waves
      #pragma unroll 1
      for (int c = wv - 1; c < 64; c += 15)
        dot8(Wh, 1024 + c*8, xv, mrz_s, 512 + c*8);
    }
    __syncthreads();

    // ---------------- B: z-chain (wave1) || M_h (waves 0,2-15) -------------
    if (wv == 1){
      float m[8], p[8], bv[8], h[8];
      #pragma unroll
      for (int e = 0; e < 8; ++e){
        const int j = l + 64*e;
        m[e] = mrz_s[512 + j]; p[e] = ps[1024 + j]; bv[e] = bias_s[1024 + j];
        h[e] = h_s[j];
      }
      float v[3];
      v[0]=0.f; v[1]=0.f;
      #pragma unroll
      for (int e = 0; e < 8; ++e){ v[0]=fmaf(h[e],h[e],v[0]); v[1]=fmaf(m[e],m[e],v[1]); }
      red64N<2>(v);
      const float hn2 = v[0];
      const float xn_h = sqrtf(hn2 + EPSF);
      const float artx_h = artanh_fast(xn_h);
      const float m2 = v[1];
      const float mn = sqrtf(m2 + EPSF);
      const float s = tanh_fast(mn/xn_h*artx_h) * (1.f/mn);
      const float x2 = s*s*m2;
      v[0]=0.f; v[1]=0.f;
      #pragma unroll
      for (int e = 0; e < 8; ++e){ v[0]=fmaf(p[e],p[e],v[0]); v[1]=fmaf(s*m[e],p[e],v[1]); }
      red64N<2>(v);
      float na = 1.f + 2.f*v[1] + v[0];
      float nb = 1.f - x2;
      float rden = 1.f / fmaxf(1.f + 2.f*v[1] + x2*v[0], EPSF);
      #pragma unroll
      for (int e = 0; e < 8; ++e) p[e] = (na*s*m[e] + nb*p[e])*rden;    // q
      v[0]=0.f; v[1]=0.f; v[2]=0.f;
      #pragma unroll
      for (int e = 0; e < 8; ++e){
        v[0]=fmaf(p[e],p[e],v[0]); v[1]=fmaf(bv[e],bv[e],v[1]); v[2]=fmaf(p[e],bv[e],v[2]);
      }
      red64N<3>(v);
      na = 1.f + 2.f*v[2] + v[1];
      nb = 1.f - v[0];
      rden = 1.f / fmaxf(1.f + 2.f*v[2] + v[0]*v[1], EPSF);
      float w2[1] = {0.f};
      #pragma unroll
      for (int e = 0; e < 8; ++e){
        m[e] = (na*p[e] + nb*bv[e])*rden;                               // w
        w2[0] = fmaf(m[e], m[e], w2[0]);
      }
      red64N<1>(w2);
      const float yn = sqrtf(w2[0] + EPSF);
      const float sc = artanh_fast(yn) * (1.f/yn);
      #pragma unroll
      for (int e = 0; e < 8; ++e) z_s[l + 64*e] = sigmoid_fast(sc*m[e]);
    } else {
      const h8 rv = *reinterpret_cast<const h8*>(&rh16_s[8*l]);
      const int slot = (wv == 0) ? 0 : wv - 1;   // 15 slots: waves {0,2..15}
      #pragma unroll 1
      for (int c = slot; c < 64; c += 15)
        dot8(Wh, 512 + c*8, rv, mh_s, c*8);
    }
    __syncthreads();

    // ---------------- finish (wave0) || next-P prefetch (waves 8-15) -------
    if (wv == 0){
      float m[8], p[8], bv[8], h[8], z[8];
      #pragma unroll
      for (int e = 0; e < 8; ++e){
        const int j = l + 64*e;
        m[e] = mh_s[j]; p[e] = ps[512 + j]; bv[e] = bias_s[512 + j];
        h[e] = h_s[j]; z[e] = z_s[j];
      }
      const float hn2 = hn2_keep;
      float v[3];
      v[0] = 0.f;
      #pragma unroll
      for (int e = 0; e < 8; ++e) v[0] = fmaf(m[e],m[e],v[0]);
      red64N<1>(v);
      const float m2 = v[0];
      const float mn = sqrtf(m2 + EPSF);
      const float s = tanh_fast(mn/xn_rh*artx_rh) * (1.f/mn);
      const float x2 = s*s*m2;
      v[0]=0.f; v[1]=0.f;
      #pragma unroll
      for (int e = 0; e < 8; ++e){ v[0]=fmaf(p[e],p[e],v[0]); v[1]=fmaf(s*m[e],p[e],v[1]); }
      red64N<2>(v);
      float na = 1.f + 2.f*v[1] + v[0];
      float nb = 1.f - x2;
      float rden = 1.f / fmaxf(1.f + 2.f*v[1] + x2*v[0], EPSF);
      #pragma unroll
      for (int e = 0; e < 8; ++e) p[e] = (na*s*m[e] + nb*p[e])*rden;    // q
      v[0]=0.f; v[1]=0.f; v[2]=0.f;
      #pragma unroll
      for (int e = 0; e < 8; ++e){
        v[0]=fmaf(p[e],p[e],v[0]); v[1]=fmaf(bv[e],bv[e],v[1]); v[2]=fmaf(p[e],bv[e],v[2]);
      }
      red64N<3>(v);
      na = 1.f + 2.f*v[2] + v[1];
      nb = 1.f - v[0];
      rden = 1.f / fmaxf(1.f + 2.f*v[2] + v[0]*v[1], EPSF);
      #pragma unroll
      for (int e = 0; e < 8; ++e) m[e] = (na*p[e] + nb*bv[e])*rden;     // ht
      v[0]=0.f; v[1]=0.f;
      #pragma unroll
      for (int e = 0; e < 8; ++e){ v[0]=fmaf(m[e],m[e],v[0]); v[1]=fmaf(h[e],m[e],v[1]); }
      red64N<2>(v);
      {
        const float y2 = v[0], hht = v[1];
        na = 1.f - 2.f*hht + y2;
        nb = 1.f - hn2;
        rden = 1.f / fmaxf(1.f - 2.f*hht + hn2*y2, EPSF);
        #pragma unroll
        for (int e = 0; e < 8; ++e) p[e] = (na*(-h[e]) + nb*m[e])*rden; // delta
      }
      v[0]=0.f; v[1]=0.f; v[2]=0.f;
      #pragma unroll
      for (int e = 0; e < 8; ++e){
        bv[e] = z[e] * p[e];                                            // wz
        v[0] = fmaf(p[e], p[e], v[0]);
        v[1] = fmaf(bv[e], bv[e], v[1]);
        v[2] = fmaf(h[e], bv[e], v[2]);
      }
      red64N<3>(v);
      const float dn  = sqrtf(v[0] + EPSF);
      const float wzn = sqrtf(v[1] + EPSF);
      const float s_pw = tanh_fast(wzn/dn*artanh_fast(dn)) * (1.f/wzn);
      const float y2f = s_pw*s_pw*v[1];
      const float xyf = s_pw*v[2];
      na = 1.f + 2.f*xyf + y2f;
      nb = 1.f - hn2;
      rden = 1.f / fmaxf(1.f + 2.f*xyf + hn2*y2f, EPSF);
      float* outp = outseq + ((size_t)t*Bn + b)*Hn;
      #pragma unroll
      for (int e = 0; e < 8; ++e){
        const int j = l + 64*e;
        const float hn = (na*h[e] + nb*s_pw*bv[e])*rden;
        h_s[j] = hn;
        h16_s[j] = (_Float16)hn;
        outp[j] = hn;
        if (t == Tn-1) lastdst[(size_t)b*Hn + j] = hn;
      }
    } else if (wv >= 8 && tt + 1 < nsteps){
      const float* pn = P + ((size_t)(tt+1)*Bn + b)*1536;
      for (int j = tid - 512; j < 1536; j += 512)
        p_s[cur ^ 1][j] = pn[j];
    }
    __syncthreads();   // h_s / h16_s / p_s ready for next step
  }
}

extern "C" void kernel_launch(void* const* d_in, const int* in_sizes, int n_in,
                              void* d_out, int out_size, void* d_ws, size_t ws_size,
                              hipStream_t stream)
{
  const float* inp  = (const float*)d_in[0];   // (T,B,H)
  const float* Wih  = (const float*)d_in[1];   // (L,3H,H)
  const float* Whh  = (const float*)d_in[2];   // (L,3H,H)
  const float* bias = (const float*)d_in[3];   // (L,3,H)
  float* out  = (float*)d_out;                 // (T,B,H)
  float* last = out + (size_t)Tn*Bn*Hn;        // (L,B,H)

  float*     P    = (float*)d_ws;                            // CHUNK*Bn x 1536
  _Float16*  Wh16 = (_Float16*)(P + (size_t)CHUNK*Bn*1536);  // 2 x 1536 x 512

  {
    const int n4 = 2*1536*512/4;
    hipLaunchKernelGGL(wconv_kernel, dim3((n4 + 255)/256), dim3(256), 0, stream,
                       Whh, Wh16, n4);
  }

  for (int l = 0; l < 2; ++l){
    const float* src    = (l == 0) ? inp : out;
    const float* Wihl   = Wih  + (size_t)l*1536*Hn;
    const _Float16* Whl = Wh16 + (size_t)l*1536*Hn;
    const float* biasl  = bias + (size_t)l*3*Hn;
    for (int c = 0; c < Tn/CHUNK; ++c){
      const int t0 = c*CHUNK;
      const float* srcc = src + (size_t)t0*Bn*Hn;
      dim3 gg(CHUNK*Bn/GBM, 1536/GBN);
      hipLaunchKernelGGL(gemm_tn, gg, dim3(256), 0, stream, srcc, Wihl, P);
      hipLaunchKernelGGL(scale_kernel, dim3(CHUNK*Bn), dim3(256), 0, stream,
                         srcc, P);
      const float* hinit = (t0 == 0) ? nullptr
                                     : out + ((size_t)(t0-1))*Bn*Hn;
      hipLaunchKernelGGL(recur_kernel, dim3(Bn), dim3(1024), 0, stream,
                         Whl, biasl, P, hinit,
                         out, last + (size_t)l*Bn*Hn, t0, CHUNK);
    }
  }
}

// Round 16
// 8064.272 us; speedup vs baseline: 3.6540x; 1.1332x over previous
//
#include <hip/hip_runtime.h>
#include <math.h>

#define Tn 256
#define Bn 64
#define Hn 512
#define CHUNK 64
#define EPSF 1e-15f
#define LOG2E 1.4426950408889634f

typedef float f32x2 __attribute__((ext_vector_type(2)));
typedef _Float16 h8 __attribute__((ext_vector_type(8)));
typedef _Float16 half2 __attribute__((ext_vector_type(2)));

// ---- hardware transcendentals with series guards ----
__device__ __forceinline__ float exp2_hw(float x){ float r; asm("v_exp_f32 %0, %1" : "=v"(r) : "v"(x)); return r; }
__device__ __forceinline__ float log2_hw(float x){ float r; asm("v_log_f32 %0, %1" : "=v"(r) : "v"(x)); return r; }
__device__ __forceinline__ float rcp_hw (float x){ float r; asm("v_rcp_f32 %0, %1" : "=v"(r) : "v"(x)); return r; }

__device__ __forceinline__ float artanh_fast(float x){   // x >= 0
  const float xc = fminf(x, 1.0f - 1e-7f);
  const float big = 0.34657359028f * (log2_hw(1.f + xc) - log2_hw(1.f - xc));
  const float x2 = x*x;
  const float small = x*(1.f + x2*(0.33333333f + x2*0.2f));
  return (x < 0.01f) ? small : big;
}
__device__ __forceinline__ float tanh_fast(float y){     // y >= 0
  const float t = exp2_hw(-2.f*LOG2E*y);
  const float big = (1.f - t) / (1.f + t);
  const float small = y*(1.f - 0.33333333f*y*y);
  return (y < 0.01f) ? small : big;
}
__device__ __forceinline__ float sigmoid_fast(float x){
  return rcp_hw(1.f + exp2_hw(-LOG2E*x));
}

// fp16 pair dot with f32 accumulate
__device__ __forceinline__ float fdot2(half2 a, half2 b, float c){
#if __has_builtin(__builtin_amdgcn_fdot2)
  return __builtin_amdgcn_fdot2(a, b, c, false);
#else
  c = fmaf((float)a[0], (float)b[0], c);
  return fmaf((float)a[1], (float)b[1], c);
#endif
}

// ---- DPP adds (VALU pipe) ----
template<int CTRL, int RM, int BM>
__device__ __forceinline__ float dpp_add(float x){
  union { float f; int i; } u, s;
  u.f = x;
  s.i = __builtin_amdgcn_update_dpp(0, u.i, CTRL, RM, BM, true);
  return x + s.f;
}
// 16-lane-group reduce: lane 15 of each group holds its group's sum
__device__ __forceinline__ float group16_sum15(float x){
  x = dpp_add<0x111,0xf,0xf>(x);   // row_shr:1
  x = dpp_add<0x112,0xf,0xf>(x);   // row_shr:2
  x = dpp_add<0x114,0xf,0xf>(x);   // row_shr:4
  x = dpp_add<0x118,0xf,0xf>(x);   // row_shr:8
  return x;
}
// full-wave sum, result at lane 63
__device__ __forceinline__ float wave_sum63(float x){
  x = dpp_add<0x111,0xf,0xf>(x);
  x = dpp_add<0x112,0xf,0xf>(x);
  x = dpp_add<0x114,0xf,0xe>(x);
  x = dpp_add<0x118,0xf,0xc>(x);
  x = dpp_add<0x142,0xa,0xf>(x);   // row_bcast:15
  x = dpp_add<0x143,0xc,0xf>(x);   // row_bcast:31
  return x;
}
__device__ __forceinline__ float bcast63(float x){
  union { float f; int i; } u; u.f = x;
  u.i = __builtin_amdgcn_readlane(u.i, 63);
  return u.f;
}
template<int N>
__device__ __forceinline__ void red64N(float* v){
  #pragma unroll
  for (int n = 0; n < N; ++n) v[n] = bcast63(wave_sum63(v[n]));
}

template<int N>
__device__ __forceinline__ void block_reduceN(float* v, float* red){
  #pragma unroll
  for (int off = 32; off > 0; off >>= 1){
    #pragma unroll
    for (int n = 0; n < N; ++n) v[n] += __shfl_xor(v[n], off);
  }
  const int tid = threadIdx.x;
  const int w = tid >> 6;
  __syncthreads();
  if ((tid & 63) == 0){
    #pragma unroll
    for (int n = 0; n < N; ++n) red[n*4 + w] = v[n];
  }
  __syncthreads();
  #pragma unroll
  for (int n = 0; n < N; ++n)
    v[n] = red[n*4+0] + red[n*4+1] + red[n*4+2] + red[n*4+3];
}

// ---------------- W fp32 -> fp16 conversion ---------------------------------
__global__ __launch_bounds__(256) void wconv_kernel(
    const float* __restrict__ W, _Float16* __restrict__ Wh, int n4)
{
  const int i = blockIdx.x*256 + threadIdx.x;
  if (i < n4){
    const float4 v = *reinterpret_cast<const float4*>(W + (size_t)i*4);
    _Float16 h4[4] = {(_Float16)v.x, (_Float16)v.y, (_Float16)v.z, (_Float16)v.w};
    *reinterpret_cast<uint2*>(Wh + (size_t)i*4) = *reinterpret_cast<uint2*>(h4);
  }
}

// ---------------- precompute GEMM ------------------------------------------
#define GBM 64
#define GBN 64
#define GBK 16

__global__ __launch_bounds__(256) void gemm_tn(
    const float* __restrict__ A, const float* __restrict__ Bm,
    float* __restrict__ Cm)
{
  __shared__ __align__(16) float As[GBK][GBM];
  __shared__ __align__(16) float Bs[GBK][GBN];
  const int tid = threadIdx.x;
  const int rm0 = blockIdx.x * GBM;
  const int cn0 = blockIdx.y * GBN;
  const int lr = tid >> 2;
  const int lk = (tid & 3) * 4;
  const int tx = tid & 15;
  const int ty = tid >> 4;
  float acc[4][4] = {};
  const float* Arow = A  + (size_t)(rm0 + lr) * 512 + lk;
  const float* Brow = Bm + (size_t)(cn0 + lr) * 512 + lk;
  for (int k0 = 0; k0 < 512; k0 += GBK){
    const float4 av = *reinterpret_cast<const float4*>(Arow + k0);
    const float4 bv = *reinterpret_cast<const float4*>(Brow + k0);
    __syncthreads();
    As[lk+0][lr]=av.x; As[lk+1][lr]=av.y; As[lk+2][lr]=av.z; As[lk+3][lr]=av.w;
    Bs[lk+0][lr]=bv.x; Bs[lk+1][lr]=bv.y; Bs[lk+2][lr]=bv.z; Bs[lk+3][lr]=bv.w;
    __syncthreads();
    #pragma unroll
    for (int kk = 0; kk < GBK; ++kk){
      const float4 a4 = *reinterpret_cast<const float4*>(&As[kk][tx*4]);
      const float4 b4 = *reinterpret_cast<const float4*>(&Bs[kk][ty*4]);
      const float ar[4] = {a4.x, a4.y, a4.z, a4.w};
      const float br[4] = {b4.x, b4.y, b4.z, b4.w};
      #pragma unroll
      for (int i = 0; i < 4; ++i)
        #pragma unroll
        for (int j = 0; j < 4; ++j)
          acc[i][j] = fmaf(ar[i], br[j], acc[i][j]);
    }
  }
  #pragma unroll
  for (int i = 0; i < 4; ++i){
    float4 st; st.x=acc[i][0]; st.y=acc[i][1]; st.z=acc[i][2]; st.w=acc[i][3];
    *reinterpret_cast<float4*>(&Cm[(size_t)(rm0 + tx*4 + i)*1536 + cn0 + ty*4]) = st;
  }
}

// ------- mobius_matvec scaling of P rows ------------------------------------
__global__ __launch_bounds__(256) void scale_kernel(
    const float* __restrict__ src, float* __restrict__ P)
{
  __shared__ float red[24];
  const int row = blockIdx.x, tid = threadIdx.x;
  const float x0 = src[(size_t)row*512 + tid];
  const float x1 = src[(size_t)row*512 + tid + 256];
  float v[3];
  v[0] = x0*x0 + x1*x1; v[1] = 0.f; v[2] = 0.f;
  block_reduceN<3>(v, red);
  const float xn = sqrtf(v[0] + EPSF);
  const float xc = fminf(fmaxf(xn, -1.0f + 1e-7f), 1.0f - 1e-7f);
  const float artx = 0.5f * (log1pf(xc) - log1pf(-xc));
  float* Prow = P + (size_t)row*1536;
  float p[6];
  #pragma unroll
  for (int g = 0; g < 3; ++g){
    p[2*g]   = Prow[g*512 + tid];
    p[2*g+1] = Prow[g*512 + tid + 256];
  }
  float m[3];
  #pragma unroll
  for (int g = 0; g < 3; ++g) m[g] = p[2*g]*p[2*g] + p[2*g+1]*p[2*g+1];
  block_reduceN<3>(m, red);
  #pragma unroll
  for (int g = 0; g < 3; ++g){
    const float mn = sqrtf(m[g] + EPSF);
    const float s = tanhf(mn / xn * artx) / mn;
    Prow[g*512 + tid]       = s * p[2*g];
    Prow[g*512 + tid + 256] = s * p[2*g+1];
  }
}

// ---------------- persistent recurrence: 1 block = 1 batch ------------------
// fp16 W + fdot2 + 4-rows-per-wave (16-lane groups, 4 DPP per 4 rows).
__global__ __launch_bounds__(1024) void recur_kernel(
    const _Float16* __restrict__ Wh,  // (1536,512) fp16: [r | hid | z]
    const float* __restrict__ bias,   // (3,512)
    const float* __restrict__ P,      // CHUNK*Bn x 1536 (scaled x-side)
    const float* __restrict__ hinit,  // (B,512) previous h, or nullptr -> zeros
    float* __restrict__ outseq,       // (T,B,H)
    float* __restrict__ lastdst,      // (B,H), written at t==Tn-1
    int t0, int nsteps)
{
  __shared__ __align__(16) float h_s[Hn];
  __shared__ __align__(16) _Float16 h16_s[Hn];
  __shared__ __align__(16) _Float16 rh16_s[Hn];
  __shared__ __align__(16) float mrz_s[1024];
  __shared__ __align__(16) float mh_s[Hn];
  __shared__ __align__(16) float z_s[Hn];
  __shared__ __align__(16) float p_s[2][1536];
  __shared__ __align__(16) float bias_s[1536];
  const int b   = blockIdx.x;
  const int tid = threadIdx.x;
  const int wv  = tid >> 6;     // wave 0..15
  const int l   = tid & 63;     // lane
  const int sl  = l & 15;       // sub-lane within 16-lane row group
  const int gg  = l >> 4;       // row-group 0..3

  for (int j = tid; j < Hn; j += 1024){
    const float hv = hinit ? hinit[(size_t)b*Hn + j] : 0.f;
    h_s[j] = hv;
    h16_s[j] = (_Float16)hv;
  }
  for (int j = tid; j < 1536; j += 1024){
    bias_s[j] = bias[j];
    p_s[0][j] = P[(size_t)b*1536 + j];
  }
  __syncthreads();

  float xn_rh = 0.f, artx_rh = 0.f, hn2_keep = 0.f;   // wave-0 step state

  // 4-row fp16 matvec: rows rowbase..rowbase+3, 16 lanes per row.
  // xq[p] = x[(p*128 + sl*8) .. +8] (same for all row groups).
  auto dot4 = [&](const _Float16* Wbase, int rowbase, const h8* xq,
                  float* dstLDS, int dstbase){
    const _Float16* wrow = Wbase + (size_t)(rowbase + gg)*Hn + sl*8;
    h8 w[4];
    #pragma unroll
    for (int p = 0; p < 4; ++p)
      w[p] = *reinterpret_cast<const h8*>(wrow + p*128);
    float a = 0.f;
    #pragma unroll
    for (int p = 0; p < 4; ++p){
      const half2* wp2 = reinterpret_cast<const half2*>(&w[p]);
      const half2* xp2 = reinterpret_cast<const half2*>(&xq[p]);
      a = fdot2(wp2[0], xp2[0], a);
      a = fdot2(wp2[1], xp2[1], a);
      a = fdot2(wp2[2], xp2[2], a);
      a = fdot2(wp2[3], xp2[3], a);
    }
    a = group16_sum15(a);
    if (sl == 15) dstLDS[dstbase + gg] = a;
  };

  for (int tt = 0; tt < nsteps; ++tt){
    const int t = t0 + tt;
    const int cur = tt & 1;
    const float* ps = p_s[cur];

    h8 xq[4];
    #pragma unroll
    for (int p = 0; p < 4; ++p)
      xq[p] = *reinterpret_cast<const h8*>(&h16_s[p*128 + sl*8]);

    // ---------------- A1: M_r (rows 0..511), all 16 waves ------------------
    #pragma unroll 1
    for (int pass = 0; pass < 8; ++pass){
      const int rb = pass*64 + wv*4;
      dot4(Wh, rb, xq, mrz_s, rb);
    }
    __syncthreads();

    // ---------------- A2: r-chain (wave0) || M_z (waves 1-15) --------------
    if (wv == 0){
      float m[8], p[8], bv[8], h[8];
      #pragma unroll
      for (int e = 0; e < 8; ++e){
        const int j = l + 64*e;
        m[e] = mrz_s[j]; p[e] = ps[j]; bv[e] = bias_s[j]; h[e] = h_s[j];
      }
      float v[3];
      v[0]=0.f; v[1]=0.f;
      #pragma unroll
      for (int e = 0; e < 8; ++e){ v[0]=fmaf(h[e],h[e],v[0]); v[1]=fmaf(m[e],m[e],v[1]); }
      red64N<2>(v);
      const float hn2 = v[0];
      const float xn_h = sqrtf(hn2 + EPSF);
      const float artx_h = artanh_fast(xn_h);
      const float m2 = v[1];
      const float mn = sqrtf(m2 + EPSF);
      const float s = tanh_fast(mn/xn_h*artx_h) * (1.f/mn);
      const float x2 = s*s*m2;
      v[0]=0.f; v[1]=0.f;
      #pragma unroll
      for (int e = 0; e < 8; ++e){ v[0]=fmaf(p[e],p[e],v[0]); v[1]=fmaf(s*m[e],p[e],v[1]); }
      red64N<2>(v);
      float na = 1.f + 2.f*v[1] + v[0];
      float nb = 1.f - x2;
      float rden = 1.f / fmaxf(1.f + 2.f*v[1] + x2*v[0], EPSF);
      #pragma unroll
      for (int e = 0; e < 8; ++e) p[e] = (na*s*m[e] + nb*p[e])*rden;    // q
      v[0]=0.f; v[1]=0.f; v[2]=0.f;
      #pragma unroll
      for (int e = 0; e < 8; ++e){
        v[0]=fmaf(p[e],p[e],v[0]); v[1]=fmaf(bv[e],bv[e],v[1]); v[2]=fmaf(p[e],bv[e],v[2]);
      }
      red64N<3>(v);
      na = 1.f + 2.f*v[2] + v[1];
      nb = 1.f - v[0];
      rden = 1.f / fmaxf(1.f + 2.f*v[2] + v[0]*v[1], EPSF);
      v[0] = 0.f;
      #pragma unroll
      for (int e = 0; e < 8; ++e){
        m[e] = (na*p[e] + nb*bv[e])*rden;                               // w
        v[0] = fmaf(m[e], m[e], v[0]);
      }
      red64N<1>(v);
      const float yn = sqrtf(v[0] + EPSF);
      const float sc = artanh_fast(yn) * (1.f/yn);
      v[0] = 0.f;
      #pragma unroll
      for (int e = 0; e < 8; ++e){
        const float r = sigmoid_fast(sc*m[e]);
        m[e] = r*h[e];                                                  // u
        v[0] = fmaf(m[e], m[e], v[0]);
      }
      red64N<1>(v);
      const float u2 = v[0];
      const float wn = sqrtf(u2 + EPSF);
      const float s_rh = tanh_fast(wn/xn_h*artx_h) * (1.f/wn);
      #pragma unroll
      for (int e = 0; e < 8; ++e) rh16_s[l + 64*e] = (_Float16)(s_rh*m[e]);
      xn_rh = sqrtf(s_rh*s_rh*u2 + EPSF);
      artx_rh = artanh_fast(xn_rh);
      hn2_keep = hn2;
    } else {
      // M_z: W rows 1024..1535 -> mrz_s[512..1023]; 128 groups over 15 waves
      #pragma unroll 1
      for (int c = wv - 1; c < 128; c += 15)
        dot4(Wh, 1024 + c*4, xq, mrz_s, 512 + c*4);
    }
    __syncthreads();

    // ---------------- B: z-chain (wave1) || M_h (waves 0,2-15) -------------
    if (wv == 1){
      float m[8], p[8], bv[8], h[8];
      #pragma unroll
      for (int e = 0; e < 8; ++e){
        const int j = l + 64*e;
        m[e] = mrz_s[512 + j]; p[e] = ps[1024 + j]; bv[e] = bias_s[1024 + j];
        h[e] = h_s[j];
      }
      float v[3];
      v[0]=0.f; v[1]=0.f;
      #pragma unroll
      for (int e = 0; e < 8; ++e){ v[0]=fmaf(h[e],h[e],v[0]); v[1]=fmaf(m[e],m[e],v[1]); }
      red64N<2>(v);
      const float hn2 = v[0];
      const float xn_h = sqrtf(hn2 + EPSF);
      const float artx_h = artanh_fast(xn_h);
      const float m2 = v[1];
      const float mn = sqrtf(m2 + EPSF);
      const float s = tanh_fast(mn/xn_h*artx_h) * (1.f/mn);
      const float x2 = s*s*m2;
      v[0]=0.f; v[1]=0.f;
      #pragma unroll
      for (int e = 0; e < 8; ++e){ v[0]=fmaf(p[e],p[e],v[0]); v[1]=fmaf(s*m[e],p[e],v[1]); }
      red64N<2>(v);
      float na = 1.f + 2.f*v[1] + v[0];
      float nb = 1.f - x2;
      float rden = 1.f / fmaxf(1.f + 2.f*v[1] + x2*v[0], EPSF);
      #pragma unroll
      for (int e = 0; e < 8; ++e) p[e] = (na*s*m[e] + nb*p[e])*rden;    // q
      v[0]=0.f; v[1]=0.f; v[2]=0.f;
      #pragma unroll
      for (int e = 0; e < 8; ++e){
        v[0]=fmaf(p[e],p[e],v[0]); v[1]=fmaf(bv[e],bv[e],v[1]); v[2]=fmaf(p[e],bv[e],v[2]);
      }
      red64N<3>(v);
      na = 1.f + 2.f*v[2] + v[1];
      nb = 1.f - v[0];
      rden = 1.f / fmaxf(1.f + 2.f*v[2] + v[0]*v[1], EPSF);
      float w2[1] = {0.f};
      #pragma unroll
      for (int e = 0; e < 8; ++e){
        m[e] = (na*p[e] + nb*bv[e])*rden;                               // w
        w2[0] = fmaf(m[e], m[e], w2[0]);
      }
      red64N<1>(w2);
      const float yn = sqrtf(w2[0] + EPSF);
      const float sc = artanh_fast(yn) * (1.f/yn);
      #pragma unroll
      for (int e = 0; e < 8; ++e) z_s[l + 64*e] = sigmoid_fast(sc*m[e]);
    } else {
      h8 rq[4];
      #pragma unroll
      for (int p = 0; p < 4; ++p)
        rq[p] = *reinterpret_cast<const h8*>(&rh16_s[p*128 + sl*8]);
      const int slot = (wv == 0) ? 0 : wv - 1;   // 15 slots: waves {0,2..15}
      #pragma unroll 1
      for (int c = slot; c < 128; c += 15)
        dot4(Wh, 512 + c*4, rq, mh_s, c*4);
    }
    __syncthreads();

    // ---------------- finish (wave0) || next-P prefetch (waves 8-15) -------
    if (wv == 0){
      float m[8], p[8], bv[8], h[8], z[8];
      #pragma unroll
      for (int e = 0; e < 8; ++e){
        const int j = l + 64*e;
        m[e] = mh_s[j]; p[e] = ps[512 + j]; bv[e] = bias_s[512 + j];
        h[e] = h_s[j]; z[e] = z_s[j];
      }
      const float hn2 = hn2_keep;
      float v[3];
      v[0] = 0.f;
      #pragma unroll
      for (int e = 0; e < 8; ++e) v[0] = fmaf(m[e],m[e],v[0]);
      red64N<1>(v);
      const float m2 = v[0];
      const float mn = sqrtf(m2 + EPSF);
      const float s = tanh_fast(mn/xn_rh*artx_rh) * (1.f/mn);
      const float x2 = s*s*m2;
      v[0]=0.f; v[1]=0.f;
      #pragma unroll
      for (int e = 0; e < 8; ++e){ v[0]=fmaf(p[e],p[e],v[0]); v[1]=fmaf(s*m[e],p[e],v[1]); }
      red64N<2>(v);
      float na = 1.f + 2.f*v[1] + v[0];
      float nb = 1.f - x2;
      float rden = 1.f / fmaxf(1.f + 2.f*v[1] + x2*v[0], EPSF);
      #pragma unroll
      for (int e = 0; e < 8; ++e) p[e] = (na*s*m[e] + nb*p[e])*rden;    // q
      v[0]=0.f; v[1]=0.f; v[2]=0.f;
      #pragma unroll
      for (int e = 0; e < 8; ++e){
        v[0]=fmaf(p[e],p[e],v[0]); v[1]=fmaf(bv[e],bv[e],v[1]); v[2]=fmaf(p[e],bv[e],v[2]);
      }
      red64N<3>(v);
      na = 1.f + 2.f*v[2] + v[1];
      nb = 1.f - v[0];
      rden = 1.f / fmaxf(1.f + 2.f*v[2] + v[0]*v[1], EPSF);
      #pragma unroll
      for (int e = 0; e < 8; ++e) m[e] = (na*p[e] + nb*bv[e])*rden;     // ht
      v[0]=0.f; v[1]=0.f;
      #pragma unroll
      for (int e = 0; e < 8; ++e){ v[0]=fmaf(m[e],m[e],v[0]); v[1]=fmaf(h[e],m[e],v[1]); }
      red64N<2>(v);
      {
        const float y2 = v[0], hht = v[1];
        na = 1.f - 2.f*hht + y2;
        nb = 1.f - hn2;
        rden = 1.f / fmaxf(1.f - 2.f*hht + hn2*y2, EPSF);
        #pragma unroll
        for (int e = 0; e < 8; ++e) p[e] = (na*(-h[e]) + nb*m[e])*rden; // delta
      }
      v[0]=0.f; v[1]=0.f; v[2]=0.f;
      #pragma unroll
      for (int e = 0; e < 8; ++e){
        bv[e] = z[e] * p[e];                                            // wz
        v[0] = fmaf(p[e], p[e], v[0]);
        v[1] = fmaf(bv[e], bv[e], v[1]);
        v[2] = fmaf(h[e], bv[e], v[2]);
      }
      red64N<3>(v);
      const float dn  = sqrtf(v[0] + EPSF);
      const float wzn = sqrtf(v[1] + EPSF);
      const float s_pw = tanh_fast(wzn/dn*artanh_fast(dn)) * (1.f/wzn);
      const float y2f = s_pw*s_pw*v[1];
      const float xyf = s_pw*v[2];
      na = 1.f + 2.f*xyf + y2f;
      nb = 1.f - hn2;
      rden = 1.f / fmaxf(1.f + 2.f*xyf + hn2*y2f, EPSF);
      float* outp = outseq + ((size_t)t*Bn + b)*Hn;
      #pragma unroll
      for (int e = 0; e < 8; ++e){
        const int j = l + 64*e;
        const float hn = (na*h[e] + nb*s_pw*bv[e])*rden;
        h_s[j] = hn;
        h16_s[j] = (_Float16)hn;
        outp[j] = hn;
        if (t == Tn-1) lastdst[(size_t)b*Hn + j] = hn;
      }
    } else if (wv >= 8 && tt + 1 < nsteps){
      const float* pn = P + ((size_t)(tt+1)*Bn + b)*1536;
      for (int j = tid - 512; j < 1536; j += 512)
        p_s[cur ^ 1][j] = pn[j];
    }
    __syncthreads();   // h_s / h16_s / p_s ready for next step
  }
}

extern "C" void kernel_launch(void* const* d_in, const int* in_sizes, int n_in,
                              void* d_out, int out_size, void* d_ws, size_t ws_size,
                              hipStream_t stream)
{
  const float* inp  = (const float*)d_in[0];   // (T,B,H)
  const float* Wih  = (const float*)d_in[1];   // (L,3H,H)
  const float* Whh  = (const float*)d_in[2];   // (L,3H,H)
  const float* bias = (const float*)d_in[3];   // (L,3,H)
  float* out  = (float*)d_out;                 // (T,B,H)
  float* last = out + (size_t)Tn*Bn*Hn;        // (L,B,H)

  float*     P    = (float*)d_ws;                            // CHUNK*Bn x 1536
  _Float16*  Wh16 = (_Float16*)(P + (size_t)CHUNK*Bn*1536);  // 2 x 1536 x 512

  {
    const int n4 = 2*1536*512/4;
    hipLaunchKernelGGL(wconv_kernel, dim3((n4 + 255)/256), dim3(256), 0, stream,
                       Whh, Wh16, n4);
  }

  for (int l = 0; l < 2; ++l){
    const float* src    = (l == 0) ? inp : out;
    const float* Wihl   = Wih  + (size_t)l*1536*Hn;
    const _Float16* Whl = Wh16 + (size_t)l*1536*Hn;
    const float* biasl  = bias + (size_t)l*3*Hn;
    for (int c = 0; c < Tn/CHUNK; ++c){
      const int t0 = c*CHUNK;
      const float* srcc = src + (size_t)t0*Bn*Hn;
      dim3 gg(CHUNK*Bn/GBM, 1536/GBN);
      hipLaunchKernelGGL(gemm_tn, gg, dim3(256), 0, stream, srcc, Wihl, P);
      hipLaunchKernelGGL(scale_kernel, dim3(CHUNK*Bn), dim3(256), 0, stream,
                         srcc, P);
      const float* hinit = (t0 == 0) ? nullptr
                                     : out + ((size_t)(t0-1))*Bn*Hn;
      hipLaunchKernelGGL(recur_kernel, dim3(Bn), dim3(1024), 0, stream,
                         Whl, biasl, P, hinit,
                         out, last + (size_t)l*Bn*Hn, t0, CHUNK);
    }
  }
}